// Round 2
// baseline (216.269 us; speedup 1.0000x reference)
//
#include <hip/hip_runtime.h>
#include <stdint.h>

typedef short bfrag __attribute__((ext_vector_type(8)));   // 8 bf16 = 4 VGPRs
typedef float f32x4 __attribute__((ext_vector_type(4)));

#define LOG2E 1.4426950408889634f

__device__ __forceinline__ ushort f2bf(float x){
  union { float f; uint32_t u; } c; c.f = x;
  uint32_t r = (c.u + 0x7fffu + ((c.u >> 16) & 1u)) >> 16;
  return (ushort)r;
}

__device__ __forceinline__ void load_lds16(const void* g, void* l){
  __builtin_amdgcn_global_load_lds((const __attribute__((address_space(1))) void*)g,
                                   (__attribute__((address_space(3))) void*)l,
                                   16, 0, 0);
}

// DPP row (16-lane) rotate; rotation butterfly is an exact all-reduce for
// commutative ops. row_ror:N ctrl = 0x120|N.
template<int CTRL>
__device__ __forceinline__ float dppf(float x){
  return __builtin_bit_cast(float, __builtin_amdgcn_update_dpp(
      0, __builtin_bit_cast(int, x), CTRL, 0xf, 0xf, true));
}
__device__ __forceinline__ float rowmax16(float x){
  x = fmaxf(x, dppf<0x128>(x));
  x = fmaxf(x, dppf<0x124>(x));
  x = fmaxf(x, dppf<0x122>(x));
  x = fmaxf(x, dppf<0x121>(x));
  return x;
}
__device__ __forceinline__ float rowsum16(float x){
  x += dppf<0x128>(x);
  x += dppf<0x124>(x);
  x += dppf<0x122>(x);
  x += dppf<0x121>(x);
  return x;
}

__global__ void cast_f32_bf16(const float* __restrict__ in, ushort* __restrict__ out, int n4){
  int i = blockIdx.x * blockDim.x + threadIdx.x;
  if (i < n4){
    float4 f = ((const float4*)in)[i];
    ushort4 u;
    u.x = f2bf(f.x); u.y = f2bf(f.y); u.z = f2bf(f.z); u.w = f2bf(f.w);
    ((ushort4*)out)[i] = u;
  }
}

// C[m,n] = sum_k A[m,k]*B[n,k] + bias[n];  A:[M,K] bf16, B:[N,K] bf16, row-major.
// EPI==1: scatter bf16 into q/k [B*NH][S][HD] and V TRANSPOSED [B*NH][HD][S].
// EPI==2: f32 into dout[M][N].
template<int EPI>
__global__ __launch_bounds__(256)
void gemm_bt(const ushort* __restrict__ A, const ushort* __restrict__ B,
             const float* __restrict__ bias,
             ushort* __restrict__ dq, ushort* __restrict__ dk, ushort* __restrict__ dvt,
             float* __restrict__ dout,
             int M, int N, int K)
{
  __shared__ ushort Alds[2][128*32];
  __shared__ ushort Blds[2][128*32];
  const int t = threadIdx.x;
  const int w = t >> 6, l = t & 63;
  const int lr = l & 15, lg = l >> 4;
  const int m0 = blockIdx.x * 128, n0 = blockIdx.y * 128;
  const int wm = (w >> 1) * 64, wn = (w & 1) * 64;

  f32x4 acc[4][4] = {};

  auto stage = [&](int buf, int kt){
#pragma unroll
    for (int i = 0; i < 2; i++){
      const int row = i*64 + w*16 + (l >> 2);
      const int ce  = (l & 3) * 8;
      load_lds16(A + (size_t)(m0 + row) * K + kt*32 + ce, &Alds[buf][(i*64 + w*16) * 32]);
      load_lds16(B + (size_t)(n0 + row) * K + kt*32 + ce, &Blds[buf][(i*64 + w*16) * 32]);
    }
  };

  const int nk = K >> 5;
  int cur = 0;
  stage(0, 0);
  __syncthreads();
  for (int kt = 0; kt < nk; kt++){
    if (kt + 1 < nk) stage(cur ^ 1, kt + 1);
    bfrag af[4], bfv[4];
#pragma unroll
    for (int f = 0; f < 4; f++){
      af[f]  = *(const bfrag*)&Alds[cur][(wm + f*16 + lr) * 32 + lg * 8];
      bfv[f] = *(const bfrag*)&Blds[cur][(wn + f*16 + lr) * 32 + lg * 8];
    }
#pragma unroll
    for (int mf = 0; mf < 4; mf++)
#pragma unroll
      for (int nf = 0; nf < 4; nf++)
        acc[mf][nf] = __builtin_amdgcn_mfma_f32_16x16x32_bf16(af[mf], bfv[nf], acc[mf][nf], 0, 0, 0);
    __syncthreads();
    cur ^= 1;
  }

#pragma unroll
  for (int mf = 0; mf < 4; mf++){
#pragma unroll
    for (int nf = 0; nf < 4; nf++){
      const int col = n0 + wn + nf*16 + lr;
      const float bs = bias[col];
#pragma unroll
      for (int r = 0; r < 4; r++){
        const int row = m0 + wm + mf*16 + lg*4 + r;
        const float vv = acc[mf][nf][r] + bs;
        if (EPI == 1){
          const int which = col >> 10;
          const int hd = col & 1023;
          const int bb = row >> 11, s = row & 2047;
          const int bh = (bb << 4) + (hd >> 6);
          if (which == 0)
            dq[((size_t)bh * 2048 + s) * 64 + (hd & 63)] = f2bf(vv);
          else if (which == 1)
            dk[((size_t)bh * 2048 + s) * 64 + (hd & 63)] = f2bf(vv);
          else
            dvt[((size_t)bh * 64 + (hd & 63)) * 2048 + s] = f2bf(vv);
        } else {
          dout[(size_t)row * N + col] = vv;
        }
      }
    }
  }
}

// Flash attention v2: one block = 64 q-rows of one (b,h); 4 waves x 16 rows.
// K tile [64 k][64 d] and Vt tile [64 d][64 k] both staged by global_load_lds
// (linear dest, inverse-swizzled source), read with byte ^ ((row&7)<<4).
// Softmax reduce via DPP row-rotations (VALU, not DS). P via swizzled per-wave
// LDS round-trip. exp2 domain.
__global__ __launch_bounds__(256)
void flash_attn(const ushort* __restrict__ q, const ushort* __restrict__ k,
                const ushort* __restrict__ vt, const float* __restrict__ mask,
                ushort* __restrict__ ao)
{
  __shared__ ushort Klds[64*64];
  __shared__ ushort Vlds[64*64];
  __shared__ ushort Plds[4][16*64];
  const int t = threadIdx.x;
  const int w = t >> 6, l = t & 63;
  const int lr = l & 15, lg = l >> 4;
  const int bh = blockIdx.y;
  const int b = bh >> 4, h = bh & 15;
  const int q0 = blockIdx.x * 64;
  const ushort* qb  = q  + (size_t)bh * 2048 * 64;
  const ushort* kb  = k  + (size_t)bh * 2048 * 64;
  const ushort* vtb = vt + (size_t)bh * 64 * 2048;
  const float* mb = mask + b * 2048;

  bfrag qf[2];
#pragma unroll
  for (int kf = 0; kf < 2; kf++){
    const int row = q0 + w*16 + lr;
    qf[kf] = *(const bfrag*)(qb + (size_t)row * 64 + kf*32 + lg*8);
  }

  float mrun[4], lrun[4];
  f32x4 oacc[4] = {};
#pragma unroll
  for (int r = 0; r < 4; r++){ mrun[r] = -1e30f; lrun[r] = 0.f; }

  const float SC2 = 0.125f * LOG2E;

  for (int kv0 = 0; kv0 < 2048; kv0 += 64){
    __syncthreads();
    // stage K [64 k][128B]: linear LDS dest, inverse-swizzled global source
#pragma unroll
    for (int i = 0; i < 2; i++){
      const int dest = i*4096 + t*16;
      const int row = dest >> 7;
      const int pc  = dest & 127;
      const char* g = (const char*)(kb + (size_t)kv0 * 64) + row*128 + (pc ^ ((row & 7) << 4));
      load_lds16(g, (char*)Klds + i*4096 + w*1024);
    }
    // stage Vt [64 d][128B window of the 4096B global row]
#pragma unroll
    for (int i = 0; i < 2; i++){
      const int dest = i*4096 + t*16;
      const int row = dest >> 7;
      const int pc  = dest & 127;
      const char* g = (const char*)vtb + (size_t)row * 4096 + kv0*2 + (pc ^ ((row & 7) << 4));
      load_lds16(g, (char*)Vlds + i*4096 + w*1024);
    }
    float mk[4];
#pragma unroll
    for (int nf = 0; nf < 4; nf++) mk[nf] = mb[kv0 + nf*16 + lr] * LOG2E;
    __syncthreads();

    // S = Q K^T
    bfrag bk[4][2];
#pragma unroll
    for (int nf = 0; nf < 4; nf++)
#pragma unroll
      for (int kf = 0; kf < 2; kf++){
        const int row = nf*16 + lr;
        const int kbyte = kf*64 + lg*16;
        bk[nf][kf] = *(const bfrag*)((const char*)Klds + row*128 + (kbyte ^ ((row & 7) << 4)));
      }
    f32x4 sa[4] = {};
#pragma unroll
    for (int nf = 0; nf < 4; nf++)
#pragma unroll
      for (int kf = 0; kf < 2; kf++)
        sa[nf] = __builtin_amdgcn_mfma_f32_16x16x32_bf16(qf[kf], bk[nf][kf], sa[nf], 0, 0, 0);

#pragma unroll
    for (int r = 0; r < 4; r++){
      float s0 = sa[0][r]*SC2 + mk[0];
      float s1 = sa[1][r]*SC2 + mk[1];
      float s2 = sa[2][r]*SC2 + mk[2];
      float s3 = sa[3][r]*SC2 + mk[3];
      float mx = fmaxf(fmaxf(s0, s1), fmaxf(s2, s3));
      mx = rowmax16(mx);
      const float mnew = fmaxf(mrun[r], mx);
      const float c = exp2f(mrun[r] - mnew);
      mrun[r] = mnew;
      const float p0 = exp2f(s0 - mnew);
      const float p1 = exp2f(s1 - mnew);
      const float p2 = exp2f(s2 - mnew);
      const float p3 = exp2f(s3 - mnew);
      float rs = rowsum16(p0 + p1 + p2 + p3);
      lrun[r] = lrun[r] * c + rs;
#pragma unroll
      for (int nf = 0; nf < 4; nf++) oacc[nf][r] *= c;
      const int prow = lg*4 + r;
      const int sw = (prow & 7) << 4;
      char* pbase = (char*)&Plds[w][0] + prow*128;
      *(ushort*)(pbase + (((lr      )*2) ^ sw)) = f2bf(p0);
      *(ushort*)(pbase + (((16 + lr )*2) ^ sw)) = f2bf(p1);
      *(ushort*)(pbase + (((32 + lr )*2) ^ sw)) = f2bf(p2);
      *(ushort*)(pbase + (((48 + lr )*2) ^ sw)) = f2bf(p3);
    }

    // O += P V   (A = P[16q][64k] from Plds, B = V[k][d] from Vt tile)
    bfrag bv[4][2], ap[2];
#pragma unroll
    for (int nf = 0; nf < 4; nf++)
#pragma unroll
      for (int kf = 0; kf < 2; kf++){
        const int d = nf*16 + lr;
        const int kbyte = kf*64 + lg*16;
        bv[nf][kf] = *(const bfrag*)((const char*)Vlds + d*128 + (kbyte ^ ((d & 7) << 4)));
      }
#pragma unroll
    for (int kf = 0; kf < 2; kf++){
      const int row = lr;
      const int kbyte = kf*64 + lg*16;
      ap[kf] = *(const bfrag*)((const char*)&Plds[w][0] + row*128 + (kbyte ^ ((row & 7) << 4)));
    }
#pragma unroll
    for (int nf = 0; nf < 4; nf++)
#pragma unroll
      for (int kf = 0; kf < 2; kf++)
        oacc[nf] = __builtin_amdgcn_mfma_f32_16x16x32_bf16(ap[kf], bv[nf][kf], oacc[nf], 0, 0, 0);
  }

#pragma unroll
  for (int nf = 0; nf < 4; nf++)
#pragma unroll
    for (int r = 0; r < 4; r++){
      const int grow = b*2048 + q0 + w*16 + lg*4 + r;
      const int col = h*64 + nf*16 + lr;
      ao[(size_t)grow * 1024 + col] = f2bf(oacc[nf][r] / lrun[r]);
    }
}

extern "C" void kernel_launch(void* const* d_in, const int* in_sizes, int n_in,
                              void* d_out, int out_size, void* d_ws, size_t ws_size,
                              hipStream_t stream)
{
  (void)in_sizes; (void)n_in; (void)out_size; (void)ws_size;
  const float* hs   = (const float*)d_in[0];
  const float* mask = (const float*)d_in[1];
  const float* wqkv = (const float*)d_in[2];
  const float* bqkv = (const float*)d_in[3];
  const float* wout = (const float*)d_in[4];
  const float* bout = (const float*)d_in[5];
  float* out = (float*)d_out;

  char* ws = (char*)d_ws;
  ushort* hs_bf = (ushort*)(ws);                 // 4096*1024   bf16 (8 MB)
  ushort* w1_bf = (ushort*)(ws + 8388608);       // 3072*1024   bf16 (6 MB)
  ushort* w2_bf = (ushort*)(ws + 14680064);      // 1024*1024   bf16 (2 MB)
  ushort* q_bf  = (ushort*)(ws + 16777216);      // [32][2048][64] bf16 (8 MB)
  ushort* k_bf  = (ushort*)(ws + 25165824);      // [32][2048][64] bf16 (8 MB)
  ushort* vt_bf = (ushort*)(ws + 33554432);      // [32][64][2048] bf16 (8 MB) TRANSPOSED
  ushort* ao_bf = (ushort*)(ws + 41943040);      // [4096][1024] bf16 (8 MB)

  cast_f32_bf16<<<4096, 256, 0, stream>>>(hs,   hs_bf, 4194304/4);
  cast_f32_bf16<<<3072, 256, 0, stream>>>(wqkv, w1_bf, 3145728/4);
  cast_f32_bf16<<<1024, 256, 0, stream>>>(wout, w2_bf, 1048576/4);

  gemm_bt<1><<<dim3(32, 24), 256, 0, stream>>>(hs_bf, w1_bf, bqkv,
                                               q_bf, k_bf, vt_bf, nullptr,
                                               4096, 3072, 1024);
  flash_attn<<<dim3(32, 32), 256, 0, stream>>>(q_bf, k_bf, vt_bf, mask, ao_bf);
  gemm_bt<2><<<dim3(32, 8), 256, 0, stream>>>(ao_bf, w2_bf, bout,
                                              nullptr, nullptr, nullptr, out,
                                              4096, 1024, 1024);
}

// Round 3
// 178.428 us; speedup vs baseline: 1.2121x; 1.2121x over previous
//
#include <hip/hip_runtime.h>
#include <stdint.h>

typedef short bfrag __attribute__((ext_vector_type(8)));   // 8 bf16 = 4 VGPRs
typedef float f32x4 __attribute__((ext_vector_type(4)));

#define LOG2E 1.4426950408889634f

__device__ __forceinline__ ushort f2bf(float x){
  union { float f; uint32_t u; } c; c.f = x;
  uint32_t r = (c.u + 0x7fffu + ((c.u >> 16) & 1u)) >> 16;
  return (ushort)r;
}

__device__ __forceinline__ void load_lds16(const void* g, void* l){
  __builtin_amdgcn_global_load_lds((const __attribute__((address_space(1))) void*)g,
                                   (__attribute__((address_space(3))) void*)l,
                                   16, 0, 0);
}

// DPP row (16-lane) rotate; rotation butterfly is an exact all-reduce.
template<int CTRL>
__device__ __forceinline__ float dppf(float x){
  return __builtin_bit_cast(float, __builtin_amdgcn_update_dpp(
      0, __builtin_bit_cast(int, x), CTRL, 0xf, 0xf, true));
}
__device__ __forceinline__ float rowmax16(float x){
  x = fmaxf(x, dppf<0x128>(x));
  x = fmaxf(x, dppf<0x124>(x));
  x = fmaxf(x, dppf<0x122>(x));
  x = fmaxf(x, dppf<0x121>(x));
  return x;
}
__device__ __forceinline__ float rowsum16(float x){
  x += dppf<0x128>(x);
  x += dppf<0x124>(x);
  x += dppf<0x122>(x);
  x += dppf<0x121>(x);
  return x;
}

__global__ void cast_f32_bf16(const float* __restrict__ in, ushort* __restrict__ out, int n4){
  int i = blockIdx.x * blockDim.x + threadIdx.x;
  if (i < n4){
    float4 f = ((const float4*)in)[i];
    ushort4 u;
    u.x = f2bf(f.x); u.y = f2bf(f.y); u.z = f2bf(f.z); u.w = f2bf(f.w);
    ((ushort4*)out)[i] = u;
  }
}

// V [bh][s][d] -> Vt [bh][d][s], 64x64 LDS tiles.
// LDS layout: byte (s*128 + x) ^ (((s>>3)&7)<<4)  (b128 writes free; transposed
// u16 reads land 2-way/bank = free).
__global__ __launch_bounds__(256)
void transpose_v(const ushort* __restrict__ v, ushort* __restrict__ vt){
  __shared__ ushort T[64*64];
  const int t = threadIdx.x;
  const int bh = blockIdx.y, s0 = blockIdx.x * 64;
  const ushort* vb = v + ((size_t)bh * 2048 + s0) * 64;
  ushort* vtb = vt + (size_t)bh * 64 * 2048 + s0;
#pragma unroll
  for (int i = 0; i < 2; i++){
    const int s = (t >> 3) + i*32, c = (t & 7) * 8;
    bfrag x = *(const bfrag*)(vb + (size_t)s * 64 + c);
    *(bfrag*)((char*)T + ((s*128 + c*2) ^ (((s >> 3) & 7) << 4))) = x;
  }
  __syncthreads();
#pragma unroll
  for (int i = 0; i < 2; i++){
    const int d = (t >> 3) + i*32, c = (t & 7) * 8;
    bfrag y;
#pragma unroll
    for (int j = 0; j < 8; j++){
      const int s = c + j;
      y[j] = *(const ushort*)((char*)T + ((s*128 + d*2) ^ (((s >> 3) & 7) << 4)));
    }
    *(bfrag*)(vtb + (size_t)d * 2048 + c) = y;
  }
}

// C[m,n] = sum_k A[m,k]*B[n,k] + bias[n];  A:[M,K] bf16, B:[N,K] bf16, row-major.
// EPI==1: scatter bf16 into q/k/v [B*NH][S][HD].  EPI==2: f32 into dout[M][N].
template<int EPI>
__global__ __launch_bounds__(256)
void gemm_bt(const ushort* __restrict__ A, const ushort* __restrict__ B,
             const float* __restrict__ bias,
             ushort* __restrict__ dq, ushort* __restrict__ dk, ushort* __restrict__ dv,
             float* __restrict__ dout,
             int M, int N, int K)
{
  __shared__ ushort Alds[2][128*32];
  __shared__ ushort Blds[2][128*32];
  const int t = threadIdx.x;
  const int w = t >> 6, l = t & 63;
  const int lr = l & 15, lg = l >> 4;
  const int m0 = blockIdx.x * 128, n0 = blockIdx.y * 128;
  const int wm = (w >> 1) * 64, wn = (w & 1) * 64;

  f32x4 acc[4][4] = {};

  auto stage = [&](int buf, int kt){
#pragma unroll
    for (int i = 0; i < 2; i++){
      const int row = i*64 + w*16 + (l >> 2);
      const int ce  = (l & 3) * 8;
      load_lds16(A + (size_t)(m0 + row) * K + kt*32 + ce, &Alds[buf][(i*64 + w*16) * 32]);
      load_lds16(B + (size_t)(n0 + row) * K + kt*32 + ce, &Blds[buf][(i*64 + w*16) * 32]);
    }
  };

  const int nk = K >> 5;
  int cur = 0;
  stage(0, 0);
  __syncthreads();
  for (int kt = 0; kt < nk; kt++){
    if (kt + 1 < nk) stage(cur ^ 1, kt + 1);
    bfrag af[4], bfv[4];
#pragma unroll
    for (int f = 0; f < 4; f++){
      af[f]  = *(const bfrag*)&Alds[cur][(wm + f*16 + lr) * 32 + lg * 8];
      bfv[f] = *(const bfrag*)&Blds[cur][(wn + f*16 + lr) * 32 + lg * 8];
    }
#pragma unroll
    for (int mf = 0; mf < 4; mf++)
#pragma unroll
      for (int nf = 0; nf < 4; nf++)
        acc[mf][nf] = __builtin_amdgcn_mfma_f32_16x16x32_bf16(af[mf], bfv[nf], acc[mf][nf], 0, 0, 0);
    __syncthreads();
    cur ^= 1;
  }

#pragma unroll
  for (int mf = 0; mf < 4; mf++){
#pragma unroll
    for (int nf = 0; nf < 4; nf++){
      const int col = n0 + wn + nf*16 + lr;
      const float bs = bias[col];
#pragma unroll
      for (int r = 0; r < 4; r++){
        const int row = m0 + wm + mf*16 + lg*4 + r;
        const float vv = acc[mf][nf][r] + bs;
        if (EPI == 1){
          const int which = col >> 10;
          const int hd = col & 1023;
          const int bb = row >> 11, s = row & 2047;
          const int bh = (bb << 4) + (hd >> 6);
          ushort* dst = (which == 0) ? dq : (which == 1) ? dk : dv;
          dst[((size_t)bh * 2048 + s) * 64 + (hd & 63)] = f2bf(vv);
        } else {
          dout[(size_t)row * N + col] = vv;
        }
      }
    }
  }
}

// Flash attention v3: one block = 64 q-rows of one (b,h); 4 waves x 16 rows.
// K [64k][64d] and Vt [64d][64k] DOUBLE-BUFFERED via global_load_lds (linear
// dest, inverse-swizzled source), ONE barrier per tile: prefetch tile t+1
// right after the barrier, compute tile t — the barrier's vmcnt(0) drain then
// waits on loads issued a full compute-phase earlier (T3-minimum pattern).
__global__ __launch_bounds__(256)
void flash_attn(const ushort* __restrict__ q, const ushort* __restrict__ k,
                const ushort* __restrict__ vt, const float* __restrict__ mask,
                ushort* __restrict__ ao)
{
  __shared__ ushort Klds[2][64*64];
  __shared__ ushort Vlds[2][64*64];
  __shared__ ushort Plds[4][16*64];
  const int t = threadIdx.x;
  const int w = t >> 6, l = t & 63;
  const int lr = l & 15, lg = l >> 4;
  const int bh = blockIdx.y;
  const int b = bh >> 4, h = bh & 15;
  const int q0 = blockIdx.x * 64;
  const ushort* qb  = q  + (size_t)bh * 2048 * 64;
  const ushort* kb  = k  + (size_t)bh * 2048 * 64;
  const ushort* vtb = vt + (size_t)bh * 64 * 2048;
  const float* mb = mask + b * 2048;

  // per-thread source-address pieces for staging (dest = linear, src pre-swizzled)
  const int srow = t >> 3;           // dest>>7 for i=0 (row 0..31), +32 for i=1
  const int spc  = (t & 7) * 16;     // dest & 127

  auto stageKV = [&](int buf, int kv0){
#pragma unroll
    for (int i = 0; i < 2; i++){
      const int row = srow + i*32;
      const int off = spc ^ ((row & 7) << 4);
      load_lds16((const char*)(kb + (size_t)kv0 * 64) + row*128 + off,
                 (char*)&Klds[buf][0] + i*4096 + w*1024);
      load_lds16((const char*)vtb + (size_t)row * 4096 + kv0*2 + off,
                 (char*)&Vlds[buf][0] + i*4096 + w*1024);
    }
  };

  bfrag qf[2];
#pragma unroll
  for (int kf = 0; kf < 2; kf++){
    const int row = q0 + w*16 + lr;
    qf[kf] = *(const bfrag*)(qb + (size_t)row * 64 + kf*32 + lg*8);
  }

  float mrun[4], lrun[4];
  f32x4 oacc[4] = {};
#pragma unroll
  for (int r = 0; r < 4; r++){ mrun[r] = -1e30f; lrun[r] = 0.f; }

  const float SC2 = 0.125f * LOG2E;

  stageKV(0, 0);
  float mk[4], mkn[4];
#pragma unroll
  for (int nf = 0; nf < 4; nf++) mk[nf] = mb[nf*16 + lr] * LOG2E;

  int cur = 0;
  for (int kv0 = 0; kv0 < 2048; kv0 += 64){
    __syncthreads();               // drains prev prefetch (vmcnt0) + protects buffers
    if (kv0 + 64 < 2048){
      stageKV(cur ^ 1, kv0 + 64);
#pragma unroll
      for (int nf = 0; nf < 4; nf++) mkn[nf] = mb[kv0 + 64 + nf*16 + lr] * LOG2E;
    }

    // S = Q K^T
    bfrag bk[4][2];
#pragma unroll
    for (int nf = 0; nf < 4; nf++)
#pragma unroll
      for (int kf = 0; kf < 2; kf++){
        const int row = nf*16 + lr;
        const int kbyte = kf*64 + lg*16;
        bk[nf][kf] = *(const bfrag*)((const char*)&Klds[cur][0] + row*128 + (kbyte ^ ((row & 7) << 4)));
      }
    f32x4 sa[4] = {};
#pragma unroll
    for (int nf = 0; nf < 4; nf++)
#pragma unroll
      for (int kf = 0; kf < 2; kf++)
        sa[nf] = __builtin_amdgcn_mfma_f32_16x16x32_bf16(qf[kf], bk[nf][kf], sa[nf], 0, 0, 0);

#pragma unroll
    for (int r = 0; r < 4; r++){
      float s0 = sa[0][r]*SC2 + mk[0];
      float s1 = sa[1][r]*SC2 + mk[1];
      float s2 = sa[2][r]*SC2 + mk[2];
      float s3 = sa[3][r]*SC2 + mk[3];
      float mx = fmaxf(fmaxf(s0, s1), fmaxf(s2, s3));
      mx = rowmax16(mx);
      const float mnew = fmaxf(mrun[r], mx);
      const float c = exp2f(mrun[r] - mnew);
      mrun[r] = mnew;
      const float p0 = exp2f(s0 - mnew);
      const float p1 = exp2f(s1 - mnew);
      const float p2 = exp2f(s2 - mnew);
      const float p3 = exp2f(s3 - mnew);
      float rs = rowsum16(p0 + p1 + p2 + p3);
      lrun[r] = lrun[r] * c + rs;
#pragma unroll
      for (int nf = 0; nf < 4; nf++) oacc[nf][r] *= c;
      const int prow = lg*4 + r;
      const int sw = (prow & 7) << 4;
      char* pbase = (char*)&Plds[w][0] + prow*128;
      *(ushort*)(pbase + (((lr      )*2) ^ sw)) = f2bf(p0);
      *(ushort*)(pbase + (((16 + lr )*2) ^ sw)) = f2bf(p1);
      *(ushort*)(pbase + (((32 + lr )*2) ^ sw)) = f2bf(p2);
      *(ushort*)(pbase + (((48 + lr )*2) ^ sw)) = f2bf(p3);
    }

    // O += P V   (A = P[16q][64k] from Plds, B from Vt tile)
    bfrag bv[4][2], ap[2];
#pragma unroll
    for (int nf = 0; nf < 4; nf++)
#pragma unroll
      for (int kf = 0; kf < 2; kf++){
        const int d = nf*16 + lr;
        const int kbyte = kf*64 + lg*16;
        bv[nf][kf] = *(const bfrag*)((const char*)&Vlds[cur][0] + d*128 + (kbyte ^ ((d & 7) << 4)));
      }
#pragma unroll
    for (int kf = 0; kf < 2; kf++){
      const int kbyte = kf*64 + lg*16;
      ap[kf] = *(const bfrag*)((const char*)&Plds[w][0] + lr*128 + (kbyte ^ ((lr & 7) << 4)));
    }
#pragma unroll
    for (int nf = 0; nf < 4; nf++)
#pragma unroll
      for (int kf = 0; kf < 2; kf++)
        oacc[nf] = __builtin_amdgcn_mfma_f32_16x16x32_bf16(ap[kf], bv[nf][kf], oacc[nf], 0, 0, 0);

#pragma unroll
    for (int nf = 0; nf < 4; nf++) mk[nf] = mkn[nf];
    cur ^= 1;
  }

#pragma unroll
  for (int nf = 0; nf < 4; nf++)
#pragma unroll
    for (int r = 0; r < 4; r++){
      const int grow = b*2048 + q0 + w*16 + lg*4 + r;
      const int col = h*64 + nf*16 + lr;
      ao[(size_t)grow * 1024 + col] = f2bf(oacc[nf][r] / lrun[r]);
    }
}

extern "C" void kernel_launch(void* const* d_in, const int* in_sizes, int n_in,
                              void* d_out, int out_size, void* d_ws, size_t ws_size,
                              hipStream_t stream)
{
  (void)in_sizes; (void)n_in; (void)out_size; (void)ws_size;
  const float* hs   = (const float*)d_in[0];
  const float* mask = (const float*)d_in[1];
  const float* wqkv = (const float*)d_in[2];
  const float* bqkv = (const float*)d_in[3];
  const float* wout = (const float*)d_in[4];
  const float* bout = (const float*)d_in[5];
  float* out = (float*)d_out;

  char* ws = (char*)d_ws;
  ushort* hs_bf = (ushort*)(ws);                 // 4096*1024   bf16 (8 MB)
  ushort* w1_bf = (ushort*)(ws + 8388608);       // 3072*1024   bf16 (6 MB)
  ushort* w2_bf = (ushort*)(ws + 14680064);      // 1024*1024   bf16 (2 MB)
  ushort* q_bf  = (ushort*)(ws + 16777216);      // [32][2048][64] bf16 (8 MB)
  ushort* k_bf  = (ushort*)(ws + 25165824);      // [32][2048][64] bf16 (8 MB)
  ushort* v_bf  = (ushort*)(ws + 33554432);      // [32][2048][64] bf16 (8 MB)
  ushort* vt_bf = (ushort*)(ws + 41943040);      // [32][64][2048] bf16 (8 MB)
  ushort* ao_bf = (ushort*)(ws + 50331648);      // [4096][1024] bf16 (8 MB)

  cast_f32_bf16<<<4096, 256, 0, stream>>>(hs,   hs_bf, 4194304/4);
  cast_f32_bf16<<<3072, 256, 0, stream>>>(wqkv, w1_bf, 3145728/4);
  cast_f32_bf16<<<1024, 256, 0, stream>>>(wout, w2_bf, 1048576/4);

  gemm_bt<1><<<dim3(32, 24), 256, 0, stream>>>(hs_bf, w1_bf, bqkv,
                                               q_bf, k_bf, v_bf, nullptr,
                                               4096, 3072, 1024);
  transpose_v<<<dim3(32, 32), 256, 0, stream>>>(v_bf, vt_bf);
  flash_attn<<<dim3(32, 32), 256, 0, stream>>>(q_bf, k_bf, vt_bf, mask, ao_bf);
  gemm_bt<2><<<dim3(32, 8), 256, 0, stream>>>(ao_bf, w2_bf, bout,
                                              nullptr, nullptr, nullptr, out,
                                              4096, 1024, 1024);
}

// Round 5
// 158.258 us; speedup vs baseline: 1.3666x; 1.1275x over previous
//
#include <hip/hip_runtime.h>
#include <stdint.h>

typedef short bfrag __attribute__((ext_vector_type(8)));   // 8 bf16 = 4 VGPRs
typedef float f32x4 __attribute__((ext_vector_type(4)));

#define LOG2E 1.4426950408889634f

__device__ __forceinline__ ushort f2bf(float x){
  union { float f; uint32_t u; } c; c.f = x;
  uint32_t r = (c.u + 0x7fffu + ((c.u >> 16) & 1u)) >> 16;
  return (ushort)r;
}

__device__ __forceinline__ uint32_t cvt_pk_bf16(float lo, float hi){
  uint32_t r;
  asm("v_cvt_pk_bf16_f32 %0, %1, %2" : "=v"(r) : "v"(lo), "v"(hi));
  return r;
}

__device__ __forceinline__ void load_lds16(const void* g, void* l){
  __builtin_amdgcn_global_load_lds((const __attribute__((address_space(1))) void*)g,
                                   (__attribute__((address_space(3))) void*)l,
                                   16, 0, 0);
}

// DPP row (16-lane) rotate; rotation butterfly is an exact all-reduce.
template<int CTRL>
__device__ __forceinline__ float dppf(float x){
  return __builtin_bit_cast(float, __builtin_amdgcn_update_dpp(
      0, __builtin_bit_cast(int, x), CTRL, 0xf, 0xf, true));
}
__device__ __forceinline__ float rowmax16(float x){
  x = fmaxf(x, dppf<0x128>(x));
  x = fmaxf(x, dppf<0x124>(x));
  x = fmaxf(x, dppf<0x122>(x));
  x = fmaxf(x, dppf<0x121>(x));
  return x;
}
__device__ __forceinline__ float rowsum16(float x){
  x += dppf<0x128>(x);
  x += dppf<0x124>(x);
  x += dppf<0x122>(x);
  x += dppf<0x121>(x);
  return x;
}

__global__ void cast_f32_bf16(const float* __restrict__ in, ushort* __restrict__ out, int n4){
  int i = blockIdx.x * blockDim.x + threadIdx.x;
  if (i < n4){
    float4 f = ((const float4*)in)[i];
    ushort4 u;
    u.x = f2bf(f.x); u.y = f2bf(f.y); u.z = f2bf(f.z); u.w = f2bf(f.w);
    ((ushort4*)out)[i] = u;
  }
}

// V [bh][s][d] -> Vt [bh][d][s], 64x64 LDS tiles.
__global__ __launch_bounds__(256)
void transpose_v(const ushort* __restrict__ v, ushort* __restrict__ vt){
  __shared__ ushort T[64*64];
  const int t = threadIdx.x;
  const int bh = blockIdx.y, s0 = blockIdx.x * 64;
  const ushort* vb = v + ((size_t)bh * 2048 + s0) * 64;
  ushort* vtb = vt + (size_t)bh * 64 * 2048 + s0;
#pragma unroll
  for (int i = 0; i < 2; i++){
    const int s = (t >> 3) + i*32, c = (t & 7) * 8;
    bfrag x = *(const bfrag*)(vb + (size_t)s * 64 + c);
    *(bfrag*)((char*)T + ((s*128 + c*2) ^ (((s >> 3) & 7) << 4))) = x;
  }
  __syncthreads();
#pragma unroll
  for (int i = 0; i < 2; i++){
    const int d = (t >> 3) + i*32, c = (t & 7) * 8;
    bfrag y;
#pragma unroll
    for (int j = 0; j < 8; j++){
      const int s = c + j;
      y[j] = *(const ushort*)((char*)T + ((s*128 + d*2) ^ (((s >> 3) & 7) << 4)));
    }
    *(bfrag*)(vtb + (size_t)d * 2048 + c) = y;
  }
}

// C[m,n] = sum_k A[m,k]*B[n,k] + bias[n];  A:[M,K] bf16, B:[N,K] bf16, row-major.
// EPI==1: scatter bf16 into q/k/v [B*NH][S][HD].  EPI==2: f32 into dout[M][N].
template<int EPI>
__global__ __launch_bounds__(256)
void gemm_bt(const ushort* __restrict__ A, const ushort* __restrict__ B,
             const float* __restrict__ bias,
             ushort* __restrict__ dq, ushort* __restrict__ dk, ushort* __restrict__ dv,
             float* __restrict__ dout,
             int M, int N, int K)
{
  __shared__ ushort Alds[2][128*32];
  __shared__ ushort Blds[2][128*32];
  const int t = threadIdx.x;
  const int w = t >> 6, l = t & 63;
  const int lr = l & 15, lg = l >> 4;
  const int m0 = blockIdx.x * 128, n0 = blockIdx.y * 128;
  const int wm = (w >> 1) * 64, wn = (w & 1) * 64;

  f32x4 acc[4][4] = {};

  auto stage = [&](int buf, int kt){
#pragma unroll
    for (int i = 0; i < 2; i++){
      const int row = i*64 + w*16 + (l >> 2);
      const int ce  = (l & 3) * 8;
      load_lds16(A + (size_t)(m0 + row) * K + kt*32 + ce, &Alds[buf][(i*64 + w*16) * 32]);
      load_lds16(B + (size_t)(n0 + row) * K + kt*32 + ce, &Blds[buf][(i*64 + w*16) * 32]);
    }
  };

  const int nk = K >> 5;
  int cur = 0;
  stage(0, 0);
  __syncthreads();
  for (int kt = 0; kt < nk; kt++){
    if (kt + 1 < nk) stage(cur ^ 1, kt + 1);
    bfrag af[4], bfv[4];
#pragma unroll
    for (int f = 0; f < 4; f++){
      af[f]  = *(const bfrag*)&Alds[cur][(wm + f*16 + lr) * 32 + lg * 8];
      bfv[f] = *(const bfrag*)&Blds[cur][(wn + f*16 + lr) * 32 + lg * 8];
    }
#pragma unroll
    for (int mf = 0; mf < 4; mf++)
#pragma unroll
      for (int nf = 0; nf < 4; nf++)
        acc[mf][nf] = __builtin_amdgcn_mfma_f32_16x16x32_bf16(af[mf], bfv[nf], acc[mf][nf], 0, 0, 0);
    __syncthreads();
    cur ^= 1;
  }

#pragma unroll
  for (int mf = 0; mf < 4; mf++){
#pragma unroll
    for (int nf = 0; nf < 4; nf++){
      const int col = n0 + wn + nf*16 + lr;
      const float bs = bias[col];
#pragma unroll
      for (int r = 0; r < 4; r++){
        const int row = m0 + wm + mf*16 + lg*4 + r;
        const float vv = acc[mf][nf][r] + bs;
        if (EPI == 1){
          const int which = col >> 10;
          const int hd = col & 1023;
          const int bb = row >> 11, s = row & 2047;
          const int bh = (bb << 4) + (hd >> 6);
          ushort* dst = (which == 0) ? dq : (which == 1) ? dk : dv;
          dst[((size_t)bh * 2048 + s) * 64 + (hd & 63)] = f2bf(vv);
        } else {
          dout[(size_t)row * N + col] = vv;
        }
      }
    }
  }
}

// Flash attention v5: double-buffered K/Vt, one barrier/tile, DPP softmax,
// cvt_pk P-conversion, defer-max (THR=8 in exp2 domain).
// P-store swizzle: XOR applied to EACH full byte offset (sw spans bits 4-6!).
__global__ __launch_bounds__(256)
void flash_attn(const ushort* __restrict__ q, const ushort* __restrict__ k,
                const ushort* __restrict__ vt, const float* __restrict__ mask,
                ushort* __restrict__ ao)
{
  __shared__ ushort Klds[2][64*64];
  __shared__ ushort Vlds[2][64*64];
  __shared__ ushort Plds[4][16*64];
  const int t = threadIdx.x;
  const int w = t >> 6, l = t & 63;
  const int lr = l & 15, lg = l >> 4;
  const int bh = blockIdx.y;
  const int b = bh >> 4, h = bh & 15;
  const int q0 = blockIdx.x * 64;
  const ushort* qb  = q  + (size_t)bh * 2048 * 64;
  const ushort* kb  = k  + (size_t)bh * 2048 * 64;
  const ushort* vtb = vt + (size_t)bh * 64 * 2048;
  const float* mb = mask + b * 2048;

  const int srow = t >> 3;
  const int spc  = (t & 7) * 16;

  auto stageKV = [&](int buf, int kv0){
#pragma unroll
    for (int i = 0; i < 2; i++){
      const int row = srow + i*32;
      const int off = spc ^ ((row & 7) << 4);
      load_lds16((const char*)(kb + (size_t)kv0 * 64) + row*128 + off,
                 (char*)&Klds[buf][0] + i*4096 + w*1024);
      load_lds16((const char*)vtb + (size_t)row * 4096 + kv0*2 + off,
                 (char*)&Vlds[buf][0] + i*4096 + w*1024);
    }
  };

  bfrag qf[2];
#pragma unroll
  for (int kf = 0; kf < 2; kf++){
    const int row = q0 + w*16 + lr;
    qf[kf] = *(const bfrag*)(qb + (size_t)row * 64 + kf*32 + lg*8);
  }

  float mrun[4], lrun[4];
  f32x4 oacc[4] = {};
#pragma unroll
  for (int r = 0; r < 4; r++){ mrun[r] = -1e30f; lrun[r] = 0.f; }

  const float SC2 = 0.125f * LOG2E;

  stageKV(0, 0);
  float mk[4], mkn[4] = {0.f, 0.f, 0.f, 0.f};
#pragma unroll
  for (int nf = 0; nf < 4; nf++) mk[nf] = mb[nf*16 + lr] * LOG2E;

  int cur = 0;
  for (int kv0 = 0; kv0 < 2048; kv0 += 64){
    __syncthreads();               // drains prev prefetch + protects buffers
    if (kv0 + 64 < 2048){
      stageKV(cur ^ 1, kv0 + 64);
#pragma unroll
      for (int nf = 0; nf < 4; nf++) mkn[nf] = mb[kv0 + 64 + nf*16 + lr] * LOG2E;
    }

    // S = Q K^T
    bfrag bk[4][2];
#pragma unroll
    for (int nf = 0; nf < 4; nf++)
#pragma unroll
      for (int kf = 0; kf < 2; kf++){
        const int row = nf*16 + lr;
        const int kbyte = kf*64 + lg*16;
        bk[nf][kf] = *(const bfrag*)((const char*)&Klds[cur][0] + row*128 + (kbyte ^ ((row & 7) << 4)));
      }
    f32x4 sa[4] = {};
#pragma unroll
    for (int nf = 0; nf < 4; nf++)
#pragma unroll
      for (int kf = 0; kf < 2; kf++)
        sa[nf] = __builtin_amdgcn_mfma_f32_16x16x32_bf16(qf[kf], bk[nf][kf], sa[nf], 0, 0, 0);

    // scaled scores sc[r][nf] (exp2 domain), tile row-max mx[r]
    float sc[4][4], mx[4];
#pragma unroll
    for (int r = 0; r < 4; r++){
#pragma unroll
      for (int nf = 0; nf < 4; nf++) sc[r][nf] = sa[nf][r]*SC2 + mk[nf];
      float m01 = fmaxf(sc[r][0], sc[r][1]);
      float m23 = fmaxf(sc[r][2], sc[r][3]);
      mx[r] = rowmax16(fmaxf(m01, m23));
    }

    // defer-max: rescale only when some row max grew by > 8 (2^8 headroom)
    const bool grew = (mx[0] > mrun[0] + 8.f) | (mx[1] > mrun[1] + 8.f) |
                      (mx[2] > mrun[2] + 8.f) | (mx[3] > mrun[3] + 8.f);
    if (!__all(!grew)){
#pragma unroll
      for (int r = 0; r < 4; r++){
        const float mnew = fmaxf(mrun[r], mx[r]);
        const float c = __builtin_amdgcn_exp2f(mrun[r] - mnew);
        mrun[r] = mnew;
        lrun[r] *= c;
#pragma unroll
        for (int nf = 0; nf < 4; nf++) oacc[nf][r] *= c;
      }
    }

    // P = exp2(sc - mrun), row-sum, pack to bf16 via cvt_pk, store swizzled.
    // NOTE: sw = (prow&7)<<4 spans byte-offset bits 4..6, so the XOR must be
    // applied to each full offset (lr*2 + {0,32,64,96}) — NOT hoisted.
#pragma unroll
    for (int r = 0; r < 4; r++){
      const float p0 = __builtin_amdgcn_exp2f(sc[r][0] - mrun[r]);
      const float p1 = __builtin_amdgcn_exp2f(sc[r][1] - mrun[r]);
      const float p2 = __builtin_amdgcn_exp2f(sc[r][2] - mrun[r]);
      const float p3 = __builtin_amdgcn_exp2f(sc[r][3] - mrun[r]);
      lrun[r] += rowsum16((p0 + p1) + (p2 + p3));
      const uint32_t w01 = cvt_pk_bf16(p0, p1);
      const uint32_t w23 = cvt_pk_bf16(p2, p3);
      const int prow = lg*4 + r;
      const int sw = (prow & 7) << 4;
      char* pbase = (char*)&Plds[w][0] + prow*128;
      *(ushort*)(pbase + ((lr*2      ) ^ sw)) = (ushort)w01;
      *(ushort*)(pbase + ((lr*2 + 32 ) ^ sw)) = (ushort)(w01 >> 16);
      *(ushort*)(pbase + ((lr*2 + 64 ) ^ sw)) = (ushort)w23;
      *(ushort*)(pbase + ((lr*2 + 96 ) ^ sw)) = (ushort)(w23 >> 16);
    }

    // O += P V
    bfrag bv[4][2], ap[2];
#pragma unroll
    for (int nf = 0; nf < 4; nf++)
#pragma unroll
      for (int kf = 0; kf < 2; kf++){
        const int d = nf*16 + lr;
        const int kbyte = kf*64 + lg*16;
        bv[nf][kf] = *(const bfrag*)((const char*)&Vlds[cur][0] + d*128 + (kbyte ^ ((d & 7) << 4)));
      }
#pragma unroll
    for (int kf = 0; kf < 2; kf++){
      const int kbyte = kf*64 + lg*16;
      ap[kf] = *(const bfrag*)((const char*)&Plds[w][0] + lr*128 + (kbyte ^ ((lr & 7) << 4)));
    }
#pragma unroll
    for (int nf = 0; nf < 4; nf++)
#pragma unroll
      for (int kf = 0; kf < 2; kf++)
        oacc[nf] = __builtin_amdgcn_mfma_f32_16x16x32_bf16(ap[kf], bv[nf][kf], oacc[nf], 0, 0, 0);

#pragma unroll
    for (int nf = 0; nf < 4; nf++) mk[nf] = mkn[nf];
    cur ^= 1;
  }

#pragma unroll
  for (int nf = 0; nf < 4; nf++)
#pragma unroll
    for (int r = 0; r < 4; r++){
      const int grow = b*2048 + q0 + w*16 + lg*4 + r;
      const int col = h*64 + nf*16 + lr;
      ao[(size_t)grow * 1024 + col] = f2bf(oacc[nf][r] / lrun[r]);
    }
}

extern "C" void kernel_launch(void* const* d_in, const int* in_sizes, int n_in,
                              void* d_out, int out_size, void* d_ws, size_t ws_size,
                              hipStream_t stream)
{
  (void)in_sizes; (void)n_in; (void)out_size; (void)ws_size;
  const float* hs   = (const float*)d_in[0];
  const float* mask = (const float*)d_in[1];
  const float* wqkv = (const float*)d_in[2];
  const float* bqkv = (const float*)d_in[3];
  const float* wout = (const float*)d_in[4];
  const float* bout = (const float*)d_in[5];
  float* out = (float*)d_out;

  char* ws = (char*)d_ws;
  ushort* hs_bf = (ushort*)(ws);                 // 4096*1024   bf16 (8 MB)
  ushort* w1_bf = (ushort*)(ws + 8388608);       // 3072*1024   bf16 (6 MB)
  ushort* w2_bf = (ushort*)(ws + 14680064);      // 1024*1024   bf16 (2 MB)
  ushort* q_bf  = (ushort*)(ws + 16777216);      // [32][2048][64] bf16 (8 MB)
  ushort* k_bf  = (ushort*)(ws + 25165824);      // [32][2048][64] bf16 (8 MB)
  ushort* v_bf  = (ushort*)(ws + 33554432);      // [32][2048][64] bf16 (8 MB)
  ushort* vt_bf = (ushort*)(ws + 41943040);      // [32][64][2048] bf16 (8 MB)
  ushort* ao_bf = (ushort*)(ws + 50331648);      // [4096][1024] bf16 (8 MB)

  cast_f32_bf16<<<4096, 256, 0, stream>>>(hs,   hs_bf, 4194304/4);
  cast_f32_bf16<<<3072, 256, 0, stream>>>(wqkv, w1_bf, 3145728/4);
  cast_f32_bf16<<<1024, 256, 0, stream>>>(wout, w2_bf, 1048576/4);

  gemm_bt<1><<<dim3(32, 24), 256, 0, stream>>>(hs_bf, w1_bf, bqkv,
                                               q_bf, k_bf, v_bf, nullptr,
                                               4096, 3072, 1024);
  transpose_v<<<dim3(32, 32), 256, 0, stream>>>(v_bf, vt_bf);
  flash_attn<<<dim3(32, 32), 256, 0, stream>>>(q_bf, k_bf, vt_bf, mask, ao_bf);
  gemm_bt<2><<<dim3(32, 8), 256, 0, stream>>>(ao_bf, w2_bf, bout,
                                              nullptr, nullptr, nullptr, out,
                                              4096, 1024, 1024);
}

// Round 6
// 147.203 us; speedup vs baseline: 1.4692x; 1.0751x over previous
//
#include <hip/hip_runtime.h>
#include <stdint.h>

typedef short bfrag __attribute__((ext_vector_type(8)));   // 8 bf16 = 4 VGPRs
typedef float f32x4 __attribute__((ext_vector_type(4)));

#define LOG2E 1.4426950408889634f

__device__ __forceinline__ ushort f2bf(float x){
  union { float f; uint32_t u; } c; c.f = x;
  uint32_t r = (c.u + 0x7fffu + ((c.u >> 16) & 1u)) >> 16;
  return (ushort)r;
}

__device__ __forceinline__ uint32_t cvt_pk_bf16(float lo, float hi){
  uint32_t r;
  asm("v_cvt_pk_bf16_f32 %0, %1, %2" : "=v"(r) : "v"(lo), "v"(hi));
  return r;
}

__device__ __forceinline__ void load_lds16(const void* g, void* l){
  __builtin_amdgcn_global_load_lds((const __attribute__((address_space(1))) void*)g,
                                   (__attribute__((address_space(3))) void*)l,
                                   16, 0, 0);
}

// DPP row (16-lane) rotate; rotation butterfly is an exact all-reduce.
template<int CTRL>
__device__ __forceinline__ float dppf(float x){
  return __builtin_bit_cast(float, __builtin_amdgcn_update_dpp(
      0, __builtin_bit_cast(int, x), CTRL, 0xf, 0xf, true));
}
__device__ __forceinline__ float rowmax16(float x){
  x = fmaxf(x, dppf<0x128>(x));
  x = fmaxf(x, dppf<0x124>(x));
  x = fmaxf(x, dppf<0x122>(x));
  x = fmaxf(x, dppf<0x121>(x));
  return x;
}
__device__ __forceinline__ float rowsum16(float x){
  x += dppf<0x128>(x);
  x += dppf<0x124>(x);
  x += dppf<0x122>(x);
  x += dppf<0x121>(x);
  return x;
}

__global__ void cast_f32_bf16(const float* __restrict__ in, ushort* __restrict__ out, int n4){
  int i = blockIdx.x * blockDim.x + threadIdx.x;
  if (i < n4){
    float4 f = ((const float4*)in)[i];
    ushort4 u;
    u.x = f2bf(f.x); u.y = f2bf(f.y); u.z = f2bf(f.z); u.w = f2bf(f.w);
    ((ushort4*)out)[i] = u;
  }
}

// V [bh][s][d] -> Vt [bh][d][s], 64x64 LDS tiles.
__global__ __launch_bounds__(256)
void transpose_v(const ushort* __restrict__ v, ushort* __restrict__ vt){
  __shared__ ushort T[64*64];
  const int t = threadIdx.x;
  const int bh = blockIdx.y, s0 = blockIdx.x * 64;
  const ushort* vb = v + ((size_t)bh * 2048 + s0) * 64;
  ushort* vtb = vt + (size_t)bh * 64 * 2048 + s0;
#pragma unroll
  for (int i = 0; i < 2; i++){
    const int s = (t >> 3) + i*32, c = (t & 7) * 8;
    bfrag x = *(const bfrag*)(vb + (size_t)s * 64 + c);
    *(bfrag*)((char*)T + ((s*128 + c*2) ^ (((s >> 3) & 7) << 4))) = x;
  }
  __syncthreads();
#pragma unroll
  for (int i = 0; i < 2; i++){
    const int d = (t >> 3) + i*32, c = (t & 7) * 8;
    bfrag y;
#pragma unroll
    for (int j = 0; j < 8; j++){
      const int s = c + j;
      y[j] = *(const ushort*)((char*)T + ((s*128 + d*2) ^ (((s >> 3) & 7) << 4)));
    }
    *(bfrag*)(vtb + (size_t)d * 2048 + c) = y;
  }
}

// C[m,n] = sum_k A[m,k]*B[n,k] + bias[n];  A:[M,K] bf16, B:[N,K] bf16, row-major.
// EPI==1: scatter bf16 into q/k/v [B*NH][S][HD].  EPI==2: f32 into dout[M][N].
template<int EPI>
__global__ __launch_bounds__(256)
void gemm_bt(const ushort* __restrict__ A, const ushort* __restrict__ B,
             const float* __restrict__ bias,
             ushort* __restrict__ dq, ushort* __restrict__ dk, ushort* __restrict__ dv,
             float* __restrict__ dout,
             int M, int N, int K)
{
  __shared__ ushort Alds[2][128*32];
  __shared__ ushort Blds[2][128*32];
  const int t = threadIdx.x;
  const int w = t >> 6, l = t & 63;
  const int lr = l & 15, lg = l >> 4;
  const int m0 = blockIdx.x * 128, n0 = blockIdx.y * 128;
  const int wm = (w >> 1) * 64, wn = (w & 1) * 64;

  f32x4 acc[4][4] = {};

  auto stage = [&](int buf, int kt){
#pragma unroll
    for (int i = 0; i < 2; i++){
      const int row = i*64 + w*16 + (l >> 2);
      const int ce  = (l & 3) * 8;
      load_lds16(A + (size_t)(m0 + row) * K + kt*32 + ce, &Alds[buf][(i*64 + w*16) * 32]);
      load_lds16(B + (size_t)(n0 + row) * K + kt*32 + ce, &Blds[buf][(i*64 + w*16) * 32]);
    }
  };

  const int nk = K >> 5;
  int cur = 0;
  stage(0, 0);
  __syncthreads();
  for (int kt = 0; kt < nk; kt++){
    if (kt + 1 < nk) stage(cur ^ 1, kt + 1);
    bfrag af[4], bfv[4];
#pragma unroll
    for (int f = 0; f < 4; f++){
      af[f]  = *(const bfrag*)&Alds[cur][(wm + f*16 + lr) * 32 + lg * 8];
      bfv[f] = *(const bfrag*)&Blds[cur][(wn + f*16 + lr) * 32 + lg * 8];
    }
#pragma unroll
    for (int mf = 0; mf < 4; mf++)
#pragma unroll
      for (int nf = 0; nf < 4; nf++)
        acc[mf][nf] = __builtin_amdgcn_mfma_f32_16x16x32_bf16(af[mf], bfv[nf], acc[mf][nf], 0, 0, 0);
    __syncthreads();
    cur ^= 1;
  }

#pragma unroll
  for (int mf = 0; mf < 4; mf++){
#pragma unroll
    for (int nf = 0; nf < 4; nf++){
      const int col = n0 + wn + nf*16 + lr;
      const float bs = bias[col];
#pragma unroll
      for (int r = 0; r < 4; r++){
        const int row = m0 + wm + mf*16 + lg*4 + r;
        const float vv = acc[mf][nf][r] + bs;
        if (EPI == 1){
          const int which = col >> 10;
          const int hd = col & 1023;
          const int bb = row >> 11, s = row & 2047;
          const int bh = (bb << 4) + (hd >> 6);
          ushort* dst = (which == 0) ? dq : (which == 1) ? dk : dv;
          dst[((size_t)bh * 2048 + s) * 64 + (hd & 63)] = f2bf(vv);
        } else {
          dout[(size_t)row * N + col] = vv;
        }
      }
    }
  }
}

// Flash attention v6: double-buffered K/Vt, one barrier/tile, cvt_pk P-pack.
// Softmax reductions minimized:
//  - rescale test = __any(lane mx4 > mrun+8)  (provably == true-rowmax test);
//    full rowmax16 chain only inside the rare rescale branch.
//  - row-sum kept as PER-LANE partial (lsum), rescaled by row-uniform c;
//    single rowsum16 in the epilogue.
__global__ __launch_bounds__(256)
void flash_attn(const ushort* __restrict__ q, const ushort* __restrict__ k,
                const ushort* __restrict__ vt, const float* __restrict__ mask,
                ushort* __restrict__ ao)
{
  __shared__ ushort Klds[2][64*64];
  __shared__ ushort Vlds[2][64*64];
  __shared__ ushort Plds[4][16*64];
  const int t = threadIdx.x;
  const int w = t >> 6, l = t & 63;
  const int lr = l & 15, lg = l >> 4;
  const int bh = blockIdx.y;
  const int b = bh >> 4, h = bh & 15;
  const int q0 = blockIdx.x * 64;
  const ushort* qb  = q  + (size_t)bh * 2048 * 64;
  const ushort* kb  = k  + (size_t)bh * 2048 * 64;
  const ushort* vtb = vt + (size_t)bh * 64 * 2048;
  const float* mb = mask + b * 2048;

  const int srow = t >> 3;
  const int spc  = (t & 7) * 16;

  auto stageKV = [&](int buf, int kv0){
#pragma unroll
    for (int i = 0; i < 2; i++){
      const int row = srow + i*32;
      const int off = spc ^ ((row & 7) << 4);
      load_lds16((const char*)(kb + (size_t)kv0 * 64) + row*128 + off,
                 (char*)&Klds[buf][0] + i*4096 + w*1024);
      load_lds16((const char*)vtb + (size_t)row * 4096 + kv0*2 + off,
                 (char*)&Vlds[buf][0] + i*4096 + w*1024);
    }
  };

  bfrag qf[2];
#pragma unroll
  for (int kf = 0; kf < 2; kf++){
    const int row = q0 + w*16 + lr;
    qf[kf] = *(const bfrag*)(qb + (size_t)row * 64 + kf*32 + lg*8);
  }

  float mrun[4], lsum[4];
  f32x4 oacc[4] = {};
#pragma unroll
  for (int r = 0; r < 4; r++){ mrun[r] = -1e30f; lsum[r] = 0.f; }

  const float SC2 = 0.125f * LOG2E;

  stageKV(0, 0);
  float mk[4], mkn[4] = {0.f, 0.f, 0.f, 0.f};
#pragma unroll
  for (int nf = 0; nf < 4; nf++) mk[nf] = mb[nf*16 + lr] * LOG2E;

  int cur = 0;
  for (int kv0 = 0; kv0 < 2048; kv0 += 64){
    __syncthreads();               // drains prev prefetch + protects buffers
    if (kv0 + 64 < 2048){
      stageKV(cur ^ 1, kv0 + 64);
#pragma unroll
      for (int nf = 0; nf < 4; nf++) mkn[nf] = mb[kv0 + 64 + nf*16 + lr] * LOG2E;
    }

    // S = Q K^T
    bfrag bk[4][2];
#pragma unroll
    for (int nf = 0; nf < 4; nf++)
#pragma unroll
      for (int kf = 0; kf < 2; kf++){
        const int row = nf*16 + lr;
        const int kbyte = kf*64 + lg*16;
        bk[nf][kf] = *(const bfrag*)((const char*)&Klds[cur][0] + row*128 + (kbyte ^ ((row & 7) << 4)));
      }
    f32x4 sa[4] = {};
#pragma unroll
    for (int nf = 0; nf < 4; nf++)
#pragma unroll
      for (int kf = 0; kf < 2; kf++)
        sa[nf] = __builtin_amdgcn_mfma_f32_16x16x32_bf16(qf[kf], bk[nf][kf], sa[nf], 0, 0, 0);

    // scaled scores (exp2 domain) + per-lane 4-col maxes
    float sc[4][4], mx4[4];
#pragma unroll
    for (int r = 0; r < 4; r++){
#pragma unroll
      for (int nf = 0; nf < 4; nf++) sc[r][nf] = sa[nf][r]*SC2 + mk[nf];
      mx4[r] = fmaxf(fmaxf(sc[r][0], sc[r][1]), fmaxf(sc[r][2], sc[r][3]));
    }

    // defer-max: any lane's own-col max exceeding its row's mrun+8 <=> some
    // row's TRUE max exceeds mrun+8 (row max == max of that row's lane mx4s).
    const bool grew = (mx4[0] > mrun[0] + 8.f) | (mx4[1] > mrun[1] + 8.f) |
                      (mx4[2] > mrun[2] + 8.f) | (mx4[3] > mrun[3] + 8.f);
    if (__any(grew)){
#pragma unroll
      for (int r = 0; r < 4; r++){
        const float mnew = fmaxf(mrun[r], rowmax16(mx4[r]));
        const float c = __builtin_amdgcn_exp2f(mrun[r] - mnew);
        mrun[r] = mnew;
        lsum[r] *= c;
#pragma unroll
        for (int nf = 0; nf < 4; nf++) oacc[nf][r] *= c;
      }
    }

    // P = exp2(sc - mrun); per-lane partial row-sum; pack & store swizzled.
    // NOTE: sw spans byte-offset bits 4..6 -> XOR each full offset (no hoist).
#pragma unroll
    for (int r = 0; r < 4; r++){
      const float p0 = __builtin_amdgcn_exp2f(sc[r][0] - mrun[r]);
      const float p1 = __builtin_amdgcn_exp2f(sc[r][1] - mrun[r]);
      const float p2 = __builtin_amdgcn_exp2f(sc[r][2] - mrun[r]);
      const float p3 = __builtin_amdgcn_exp2f(sc[r][3] - mrun[r]);
      lsum[r] += (p0 + p1) + (p2 + p3);
      const uint32_t w01 = cvt_pk_bf16(p0, p1);
      const uint32_t w23 = cvt_pk_bf16(p2, p3);
      const int prow = lg*4 + r;
      const int sw = (prow & 7) << 4;
      char* pbase = (char*)&Plds[w][0] + prow*128;
      *(ushort*)(pbase + ((lr*2      ) ^ sw)) = (ushort)w01;
      *(ushort*)(pbase + ((lr*2 + 32 ) ^ sw)) = (ushort)(w01 >> 16);
      *(ushort*)(pbase + ((lr*2 + 64 ) ^ sw)) = (ushort)w23;
      *(ushort*)(pbase + ((lr*2 + 96 ) ^ sw)) = (ushort)(w23 >> 16);
    }

    // O += P V
    bfrag bv[4][2], ap[2];
#pragma unroll
    for (int nf = 0; nf < 4; nf++)
#pragma unroll
      for (int kf = 0; kf < 2; kf++){
        const int d = nf*16 + lr;
        const int kbyte = kf*64 + lg*16;
        bv[nf][kf] = *(const bfrag*)((const char*)&Vlds[cur][0] + d*128 + (kbyte ^ ((d & 7) << 4)));
      }
#pragma unroll
    for (int kf = 0; kf < 2; kf++){
      const int kbyte = kf*64 + lg*16;
      ap[kf] = *(const bfrag*)((const char*)&Plds[w][0] + lr*128 + (kbyte ^ ((lr & 7) << 4)));
    }
#pragma unroll
    for (int nf = 0; nf < 4; nf++)
#pragma unroll
      for (int kf = 0; kf < 2; kf++)
        oacc[nf] = __builtin_amdgcn_mfma_f32_16x16x32_bf16(ap[kf], bv[nf][kf], oacc[nf], 0, 0, 0);

#pragma unroll
    for (int nf = 0; nf < 4; nf++) mk[nf] = mkn[nf];
    cur ^= 1;
  }

  // epilogue: single cross-lane row-sum, then divide & store
#pragma unroll
  for (int r = 0; r < 4; r++){
    const float inv = 1.f / rowsum16(lsum[r]);
#pragma unroll
    for (int nf = 0; nf < 4; nf++){
      const int grow = b*2048 + q0 + w*16 + lg*4 + r;
      const int col = h*64 + nf*16 + lr;
      ao[(size_t)grow * 1024 + col] = f2bf(oacc[nf][r] * inv);
    }
  }
}

extern "C" void kernel_launch(void* const* d_in, const int* in_sizes, int n_in,
                              void* d_out, int out_size, void* d_ws, size_t ws_size,
                              hipStream_t stream)
{
  (void)in_sizes; (void)n_in; (void)out_size; (void)ws_size;
  const float* hs   = (const float*)d_in[0];
  const float* mask = (const float*)d_in[1];
  const float* wqkv = (const float*)d_in[2];
  const float* bqkv = (const float*)d_in[3];
  const float* wout = (const float*)d_in[4];
  const float* bout = (const float*)d_in[5];
  float* out = (float*)d_out;

  char* ws = (char*)d_ws;
  ushort* hs_bf = (ushort*)(ws);                 // 4096*1024   bf16 (8 MB)
  ushort* w1_bf = (ushort*)(ws + 8388608);       // 3072*1024   bf16 (6 MB)
  ushort* w2_bf = (ushort*)(ws + 14680064);      // 1024*1024   bf16 (2 MB)
  ushort* q_bf  = (ushort*)(ws + 16777216);      // [32][2048][64] bf16 (8 MB)
  ushort* k_bf  = (ushort*)(ws + 25165824);      // [32][2048][64] bf16 (8 MB)
  ushort* v_bf  = (ushort*)(ws + 33554432);      // [32][2048][64] bf16 (8 MB)
  ushort* vt_bf = (ushort*)(ws + 41943040);      // [32][64][2048] bf16 (8 MB)
  ushort* ao_bf = (ushort*)(ws + 50331648);      // [4096][1024] bf16 (8 MB)

  cast_f32_bf16<<<4096, 256, 0, stream>>>(hs,   hs_bf, 4194304/4);
  cast_f32_bf16<<<3072, 256, 0, stream>>>(wqkv, w1_bf, 3145728/4);
  cast_f32_bf16<<<1024, 256, 0, stream>>>(wout, w2_bf, 1048576/4);

  gemm_bt<1><<<dim3(32, 24), 256, 0, stream>>>(hs_bf, w1_bf, bqkv,
                                               q_bf, k_bf, v_bf, nullptr,
                                               4096, 3072, 1024);
  transpose_v<<<dim3(32, 32), 256, 0, stream>>>(v_bf, vt_bf);
  flash_attn<<<dim3(32, 32), 256, 0, stream>>>(q_bf, k_bf, vt_bf, mask, ao_bf);
  gemm_bt<2><<<dim3(32, 8), 256, 0, stream>>>(ao_bf, w2_bf, bout,
                                              nullptr, nullptr, nullptr, out,
                                              4096, 1024, 1024);
}

// Round 7
// 136.042 us; speedup vs baseline: 1.5897x; 1.0820x over previous
//
#include <hip/hip_runtime.h>
#include <stdint.h>

typedef short bfrag __attribute__((ext_vector_type(8)));   // 8 bf16 = 4 VGPRs
typedef float f32x4 __attribute__((ext_vector_type(4)));

#define LOG2E 1.4426950408889634f

__device__ __forceinline__ ushort f2bf(float x){
  union { float f; uint32_t u; } c; c.f = x;
  uint32_t r = (c.u + 0x7fffu + ((c.u >> 16) & 1u)) >> 16;
  return (ushort)r;
}

__device__ __forceinline__ uint32_t cvt_pk_bf16(float lo, float hi){
  uint32_t r;
  asm("v_cvt_pk_bf16_f32 %0, %1, %2" : "=v"(r) : "v"(lo), "v"(hi));
  return r;
}

__device__ __forceinline__ void load_lds16(const void* g, void* l){
  __builtin_amdgcn_global_load_lds((const __attribute__((address_space(1))) void*)g,
                                   (__attribute__((address_space(3))) void*)l,
                                   16, 0, 0);
}

// DPP row (16-lane) rotate; rotation butterfly is an exact all-reduce.
template<int CTRL>
__device__ __forceinline__ float dppf(float x){
  return __builtin_bit_cast(float, __builtin_amdgcn_update_dpp(
      0, __builtin_bit_cast(int, x), CTRL, 0xf, 0xf, true));
}
__device__ __forceinline__ float rowmax16(float x){
  x = fmaxf(x, dppf<0x128>(x));
  x = fmaxf(x, dppf<0x124>(x));
  x = fmaxf(x, dppf<0x122>(x));
  x = fmaxf(x, dppf<0x121>(x));
  return x;
}
__device__ __forceinline__ float rowsum16(float x){
  x += dppf<0x128>(x);
  x += dppf<0x124>(x);
  x += dppf<0x122>(x);
  x += dppf<0x121>(x);
  return x;
}

// One merged cast kernel: destinations are contiguous in ws
// (hs_bf | w1_bf | w2_bf), sources are three input pointers.
__global__ void cast_all(const float* __restrict__ hs, const float* __restrict__ wqkv,
                         const float* __restrict__ wout, ushort* __restrict__ out){
  const int i = blockIdx.x * blockDim.x + threadIdx.x;     // float4 index
  float4 f;
  if (i < 1048576)       f = ((const float4*)hs)[i];
  else if (i < 1835008)  f = ((const float4*)wqkv)[i - 1048576];
  else                   f = ((const float4*)wout)[i - 1835008];
  ushort4 u;
  u.x = f2bf(f.x); u.y = f2bf(f.y); u.z = f2bf(f.z); u.w = f2bf(f.w);
  ((ushort4*)out)[i] = u;
}

// V [bh][s][d] -> Vt [bh][d][s], 64x64 LDS tiles.
__global__ __launch_bounds__(256)
void transpose_v(const ushort* __restrict__ v, ushort* __restrict__ vt){
  __shared__ ushort T[64*64];
  const int t = threadIdx.x;
  const int bh = blockIdx.y, s0 = blockIdx.x * 64;
  const ushort* vb = v + ((size_t)bh * 2048 + s0) * 64;
  ushort* vtb = vt + (size_t)bh * 64 * 2048 + s0;
#pragma unroll
  for (int i = 0; i < 2; i++){
    const int s = (t >> 3) + i*32, c = (t & 7) * 8;
    bfrag x = *(const bfrag*)(vb + (size_t)s * 64 + c);
    *(bfrag*)((char*)T + ((s*128 + c*2) ^ (((s >> 3) & 7) << 4))) = x;
  }
  __syncthreads();
#pragma unroll
  for (int i = 0; i < 2; i++){
    const int d = (t >> 3) + i*32, c = (t & 7) * 8;
    bfrag y;
#pragma unroll
    for (int j = 0; j < 8; j++){
      const int s = c + j;
      y[j] = *(const ushort*)((char*)T + ((s*128 + d*2) ^ (((s >> 3) & 7) << 4)));
    }
    *(bfrag*)(vtb + (size_t)d * 2048 + c) = y;
  }
}

// C[m,n] = sum_k A[m,k]*B[n,k] + bias[n];  A:[M,K] bf16, B:[N,K] bf16, row-major.
// EPI==1: scatter bf16 into q/k/v [B*NH][S][HD].  EPI==2: f32 into dout[M][N].
template<int EPI>
__global__ __launch_bounds__(256)
void gemm_bt(const ushort* __restrict__ A, const ushort* __restrict__ B,
             const float* __restrict__ bias,
             ushort* __restrict__ dq, ushort* __restrict__ dk, ushort* __restrict__ dv,
             float* __restrict__ dout,
             int M, int N, int K)
{
  __shared__ ushort Alds[2][128*32];
  __shared__ ushort Blds[2][128*32];
  const int t = threadIdx.x;
  const int w = t >> 6, l = t & 63;
  const int lr = l & 15, lg = l >> 4;
  const int m0 = blockIdx.x * 128, n0 = blockIdx.y * 128;
  const int wm = (w >> 1) * 64, wn = (w & 1) * 64;

  f32x4 acc[4][4] = {};

  auto stage = [&](int buf, int kt){
#pragma unroll
    for (int i = 0; i < 2; i++){
      const int row = i*64 + w*16 + (l >> 2);
      const int ce  = (l & 3) * 8;
      load_lds16(A + (size_t)(m0 + row) * K + kt*32 + ce, &Alds[buf][(i*64 + w*16) * 32]);
      load_lds16(B + (size_t)(n0 + row) * K + kt*32 + ce, &Blds[buf][(i*64 + w*16) * 32]);
    }
  };

  const int nk = K >> 5;
  int cur = 0;
  stage(0, 0);
  __syncthreads();
  for (int kt = 0; kt < nk; kt++){
    if (kt + 1 < nk) stage(cur ^ 1, kt + 1);
    bfrag af[4], bfv[4];
#pragma unroll
    for (int f = 0; f < 4; f++){
      af[f]  = *(const bfrag*)&Alds[cur][(wm + f*16 + lr) * 32 + lg * 8];
      bfv[f] = *(const bfrag*)&Blds[cur][(wn + f*16 + lr) * 32 + lg * 8];
    }
#pragma unroll
    for (int mf = 0; mf < 4; mf++)
#pragma unroll
      for (int nf = 0; nf < 4; nf++)
        acc[mf][nf] = __builtin_amdgcn_mfma_f32_16x16x32_bf16(af[mf], bfv[nf], acc[mf][nf], 0, 0, 0);
    __syncthreads();
    cur ^= 1;
  }

#pragma unroll
  for (int mf = 0; mf < 4; mf++){
#pragma unroll
    for (int nf = 0; nf < 4; nf++){
      const int col = n0 + wn + nf*16 + lr;
      const float bs = bias[col];
#pragma unroll
      for (int r = 0; r < 4; r++){
        const int row = m0 + wm + mf*16 + lg*4 + r;
        const float vv = acc[mf][nf][r] + bs;
        if (EPI == 1){
          const int which = col >> 10;
          const int hd = col & 1023;
          const int bb = row >> 11, s = row & 2047;
          const int bh = (bb << 4) + (hd >> 6);
          ushort* dst = (which == 0) ? dq : (which == 1) ? dk : dv;
          dst[((size_t)bh * 2048 + s) * 64 + (hd & 63)] = f2bf(vv);
        } else {
          dout[(size_t)row * N + col] = vv;
        }
      }
    }
  }
}

// Flash attention v7: 8-wave blocks (QBLK=128, 512 threads) — each staged K/Vt
// tile serves 8 waves (staging per wave halves), grid 512 blocks = 2/CU with
// 48KB LDS -> ~16 waves/CU. Per-wave math identical to v6: double-buffered
// K/Vt, one barrier/tile, cheap defer-max test, per-lane partial row-sum,
// cvt_pk P-pack, swizzled P round-trip.
__global__ __launch_bounds__(512, 4)
void flash_attn(const ushort* __restrict__ q, const ushort* __restrict__ k,
                const ushort* __restrict__ vt, const float* __restrict__ mask,
                ushort* __restrict__ ao)
{
  __shared__ ushort Klds[2][64*64];
  __shared__ ushort Vlds[2][64*64];
  __shared__ ushort Plds[8][16*64];
  const int t = threadIdx.x;
  const int w = t >> 6, l = t & 63;
  const int lr = l & 15, lg = l >> 4;
  const int bh = blockIdx.y;
  const int b = bh >> 4, h = bh & 15;
  const int q0 = blockIdx.x * 128;
  const ushort* qb  = q  + (size_t)bh * 2048 * 64;
  const ushort* kb  = k  + (size_t)bh * 2048 * 64;
  const ushort* vtb = vt + (size_t)bh * 64 * 2048;
  const float* mb = mask + b * 2048;

  // 512 threads stage one 64x64 K tile + one 64x64 Vt tile: 1 load each.
  const int srow = t >> 3;           // 0..63
  const int spc  = (t & 7) * 16;

  auto stageKV = [&](int buf, int kv0){
    const int off = spc ^ ((srow & 7) << 4);
    load_lds16((const char*)(kb + (size_t)kv0 * 64) + srow*128 + off,
               (char*)&Klds[buf][0] + w*1024);
    load_lds16((const char*)vtb + (size_t)srow * 4096 + kv0*2 + off,
               (char*)&Vlds[buf][0] + w*1024);
  };

  bfrag qf[2];
#pragma unroll
  for (int kf = 0; kf < 2; kf++){
    const int row = q0 + w*16 + lr;
    qf[kf] = *(const bfrag*)(qb + (size_t)row * 64 + kf*32 + lg*8);
  }

  float mrun[4], lsum[4];
  f32x4 oacc[4] = {};
#pragma unroll
  for (int r = 0; r < 4; r++){ mrun[r] = -1e30f; lsum[r] = 0.f; }

  const float SC2 = 0.125f * LOG2E;

  stageKV(0, 0);
  float mk[4], mkn[4] = {0.f, 0.f, 0.f, 0.f};
#pragma unroll
  for (int nf = 0; nf < 4; nf++) mk[nf] = mb[nf*16 + lr] * LOG2E;

  int cur = 0;
  for (int kv0 = 0; kv0 < 2048; kv0 += 64){
    __syncthreads();               // drains prev prefetch + protects buffers
    if (kv0 + 64 < 2048){
      stageKV(cur ^ 1, kv0 + 64);
#pragma unroll
      for (int nf = 0; nf < 4; nf++) mkn[nf] = mb[kv0 + 64 + nf*16 + lr] * LOG2E;
    }

    // S = Q K^T
    bfrag bk[4][2];
#pragma unroll
    for (int nf = 0; nf < 4; nf++)
#pragma unroll
      for (int kf = 0; kf < 2; kf++){
        const int row = nf*16 + lr;
        const int kbyte = kf*64 + lg*16;
        bk[nf][kf] = *(const bfrag*)((const char*)&Klds[cur][0] + row*128 + (kbyte ^ ((row & 7) << 4)));
      }
    f32x4 sa[4] = {};
#pragma unroll
    for (int nf = 0; nf < 4; nf++)
#pragma unroll
      for (int kf = 0; kf < 2; kf++)
        sa[nf] = __builtin_amdgcn_mfma_f32_16x16x32_bf16(qf[kf], bk[nf][kf], sa[nf], 0, 0, 0);

    // scaled scores (exp2 domain) + per-lane 4-col maxes
    float sc[4][4], mx4[4];
#pragma unroll
    for (int r = 0; r < 4; r++){
#pragma unroll
      for (int nf = 0; nf < 4; nf++) sc[r][nf] = sa[nf][r]*SC2 + mk[nf];
      mx4[r] = fmaxf(fmaxf(sc[r][0], sc[r][1]), fmaxf(sc[r][2], sc[r][3]));
    }

    // defer-max: any lane's own-col max exceeding its row's mrun+8 <=> some
    // row's TRUE max exceeds mrun+8.
    const bool grew = (mx4[0] > mrun[0] + 8.f) | (mx4[1] > mrun[1] + 8.f) |
                      (mx4[2] > mrun[2] + 8.f) | (mx4[3] > mrun[3] + 8.f);
    if (__any(grew)){
#pragma unroll
      for (int r = 0; r < 4; r++){
        const float mnew = fmaxf(mrun[r], rowmax16(mx4[r]));
        const float c = __builtin_amdgcn_exp2f(mrun[r] - mnew);
        mrun[r] = mnew;
        lsum[r] *= c;
#pragma unroll
        for (int nf = 0; nf < 4; nf++) oacc[nf][r] *= c;
      }
    }

    // P = exp2(sc - mrun); per-lane partial row-sum; pack & store swizzled.
    // NOTE: sw spans byte-offset bits 4..6 -> XOR each full offset (no hoist).
#pragma unroll
    for (int r = 0; r < 4; r++){
      const float p0 = __builtin_amdgcn_exp2f(sc[r][0] - mrun[r]);
      const float p1 = __builtin_amdgcn_exp2f(sc[r][1] - mrun[r]);
      const float p2 = __builtin_amdgcn_exp2f(sc[r][2] - mrun[r]);
      const float p3 = __builtin_amdgcn_exp2f(sc[r][3] - mrun[r]);
      lsum[r] += (p0 + p1) + (p2 + p3);
      const uint32_t w01 = cvt_pk_bf16(p0, p1);
      const uint32_t w23 = cvt_pk_bf16(p2, p3);
      const int prow = lg*4 + r;
      const int sw = (prow & 7) << 4;
      char* pbase = (char*)&Plds[w][0] + prow*128;
      *(ushort*)(pbase + ((lr*2      ) ^ sw)) = (ushort)w01;
      *(ushort*)(pbase + ((lr*2 + 32 ) ^ sw)) = (ushort)(w01 >> 16);
      *(ushort*)(pbase + ((lr*2 + 64 ) ^ sw)) = (ushort)w23;
      *(ushort*)(pbase + ((lr*2 + 96 ) ^ sw)) = (ushort)(w23 >> 16);
    }

    // O += P V
    bfrag bv[4][2], ap[2];
#pragma unroll
    for (int nf = 0; nf < 4; nf++)
#pragma unroll
      for (int kf = 0; kf < 2; kf++){
        const int d = nf*16 + lr;
        const int kbyte = kf*64 + lg*16;
        bv[nf][kf] = *(const bfrag*)((const char*)&Vlds[cur][0] + d*128 + (kbyte ^ ((d & 7) << 4)));
      }
#pragma unroll
    for (int kf = 0; kf < 2; kf++){
      const int kbyte = kf*64 + lg*16;
      ap[kf] = *(const bfrag*)((const char*)&Plds[w][0] + lr*128 + (kbyte ^ ((lr & 7) << 4)));
    }
#pragma unroll
    for (int nf = 0; nf < 4; nf++)
#pragma unroll
      for (int kf = 0; kf < 2; kf++)
        oacc[nf] = __builtin_amdgcn_mfma_f32_16x16x32_bf16(ap[kf], bv[nf][kf], oacc[nf], 0, 0, 0);

#pragma unroll
    for (int nf = 0; nf < 4; nf++) mk[nf] = mkn[nf];
    cur ^= 1;
  }

  // epilogue: single cross-lane row-sum, then divide & store
#pragma unroll
  for (int r = 0; r < 4; r++){
    const float inv = 1.f / rowsum16(lsum[r]);
#pragma unroll
    for (int nf = 0; nf < 4; nf++){
      const int grow = b*2048 + q0 + w*16 + lg*4 + r;
      const int col = h*64 + nf*16 + lr;
      ao[(size_t)grow * 1024 + col] = f2bf(oacc[nf][r] * inv);
    }
  }
}

extern "C" void kernel_launch(void* const* d_in, const int* in_sizes, int n_in,
                              void* d_out, int out_size, void* d_ws, size_t ws_size,
                              hipStream_t stream)
{
  (void)in_sizes; (void)n_in; (void)out_size; (void)ws_size;
  const float* hs   = (const float*)d_in[0];
  const float* mask = (const float*)d_in[1];
  const float* wqkv = (const float*)d_in[2];
  const float* bqkv = (const float*)d_in[3];
  const float* wout = (const float*)d_in[4];
  const float* bout = (const float*)d_in[5];
  float* out = (float*)d_out;

  char* ws = (char*)d_ws;
  ushort* hs_bf = (ushort*)(ws);                 // 4096*1024   bf16 (8 MB)
  ushort* w1_bf = (ushort*)(ws + 8388608);       // 3072*1024   bf16 (6 MB)
  ushort* w2_bf = (ushort*)(ws + 14680064);      // 1024*1024   bf16 (2 MB)
  ushort* q_bf  = (ushort*)(ws + 16777216);      // [32][2048][64] bf16 (8 MB)
  ushort* k_bf  = (ushort*)(ws + 25165824);      // [32][2048][64] bf16 (8 MB)
  ushort* v_bf  = (ushort*)(ws + 33554432);      // [32][2048][64] bf16 (8 MB)
  ushort* vt_bf = (ushort*)(ws + 41943040);      // [32][64][2048] bf16 (8 MB)
  ushort* ao_bf = (ushort*)(ws + 50331648);      // [4096][1024] bf16 (8 MB)

  cast_all<<<8192, 256, 0, stream>>>(hs, wqkv, wout, (ushort*)ws);

  gemm_bt<1><<<dim3(32, 24), 256, 0, stream>>>(hs_bf, w1_bf, bqkv,
                                               q_bf, k_bf, v_bf, nullptr,
                                               4096, 3072, 1024);
  transpose_v<<<dim3(32, 32), 256, 0, stream>>>(v_bf, vt_bf);
  flash_attn<<<dim3(16, 32), 512, 0, stream>>>(q_bf, k_bf, vt_bf, mask, ao_bf);
  gemm_bt<2><<<dim3(32, 8), 256, 0, stream>>>(ao_bf, w2_bf, bout,
                                              nullptr, nullptr, nullptr, out,
                                              4096, 1024, 1024);
}

// Round 9
// 128.553 us; speedup vs baseline: 1.6823x; 1.0583x over previous
//
#include <hip/hip_runtime.h>
#include <stdint.h>

typedef short bfrag __attribute__((ext_vector_type(8)));   // 8 bf16 = 4 VGPRs
typedef float f32x4 __attribute__((ext_vector_type(4)));
typedef uint  uint4v __attribute__((ext_vector_type(4)));
typedef uint  uint2v __attribute__((ext_vector_type(2)));

#define LOG2E 1.4426950408889634f
// LDS row swizzle: spreads rows {0-3 mod 8} AND consecutive rows across slots.
#define SWZ(row) ((((row) & 3) | (((row) >> 1) & 4)) << 4)

__device__ __forceinline__ ushort f2bf(float x){
  union { float f; uint32_t u; } c; c.f = x;
  uint32_t r = (c.u + 0x7fffu + ((c.u >> 16) & 1u)) >> 16;
  return (ushort)r;
}

__device__ __forceinline__ uint32_t cvt_pk_bf16(float lo, float hi){
  uint32_t r;
  asm("v_cvt_pk_bf16_f32 %0, %1, %2" : "=v"(r) : "v"(lo), "v"(hi));
  return r;
}

// cross-lane reduce over lanes {lr, lr+16, lr+32, lr+48} — __shfl_xor has
// unambiguous semantics (ds_swizzle/bpermute under the hood); OFF the hot path.
__device__ __forceinline__ float redq_max(float x){
  x = fmaxf(x, __shfl_xor(x, 16));
  x = fmaxf(x, __shfl_xor(x, 32));
  return x;
}
__device__ __forceinline__ float redq_sum(float x){
  x += __shfl_xor(x, 16);
  x += __shfl_xor(x, 32);
  return x;
}

__device__ __forceinline__ void load_lds16(const void* g, void* l){
  __builtin_amdgcn_global_load_lds((const __attribute__((address_space(1))) void*)g,
                                   (__attribute__((address_space(3))) void*)l,
                                   16, 0, 0);
}

// Merged cast: hs|wqkv|wout -> bf16 (contiguous in ws), plus mask*LOG2E -> f32.
__global__ void cast_all(const float* __restrict__ hs, const float* __restrict__ wqkv,
                         const float* __restrict__ wout, const float* __restrict__ mask,
                         ushort* __restrict__ out, float* __restrict__ mask2){
  const int i = blockIdx.x * blockDim.x + threadIdx.x;     // float4 index
  if (i < 2097152){
    float4 f;
    if (i < 1048576)       f = ((const float4*)hs)[i];
    else if (i < 1835008)  f = ((const float4*)wqkv)[i - 1048576];
    else                   f = ((const float4*)wout)[i - 1835008];
    ushort4 u;
    u.x = f2bf(f.x); u.y = f2bf(f.y); u.z = f2bf(f.z); u.w = f2bf(f.w);
    ((ushort4*)out)[i] = u;
  } else {
    const int j = i - 2097152;                             // 1024 float4s of mask
    float4 m = ((const float4*)mask)[j];
    m.x *= LOG2E; m.y *= LOG2E; m.z *= LOG2E; m.w *= LOG2E;
    ((float4*)mask2)[j] = m;
  }
}

// V [bh][s][d] -> Vt [bh][d][s], 64x64 LDS tiles.
__global__ __launch_bounds__(256)
void transpose_v(const ushort* __restrict__ v, ushort* __restrict__ vt){
  __shared__ ushort T[64*64];
  const int t = threadIdx.x;
  const int bh = blockIdx.y, s0 = blockIdx.x * 64;
  const ushort* vb = v + ((size_t)bh * 2048 + s0) * 64;
  ushort* vtb = vt + (size_t)bh * 64 * 2048 + s0;
#pragma unroll
  for (int i = 0; i < 2; i++){
    const int s = (t >> 3) + i*32, c = (t & 7) * 8;
    bfrag x = *(const bfrag*)(vb + (size_t)s * 64 + c);
    *(bfrag*)((char*)T + ((s*128 + c*2) ^ (((s >> 3) & 7) << 4))) = x;
  }
  __syncthreads();
#pragma unroll
  for (int i = 0; i < 2; i++){
    const int d = (t >> 3) + i*32, c = (t & 7) * 8;
    bfrag y;
#pragma unroll
    for (int j = 0; j < 8; j++){
      const int s = c + j;
      y[j] = *(const ushort*)((char*)T + ((s*128 + d*2) ^ (((s >> 3) & 7) << 4)));
    }
    *(bfrag*)(vtb + (size_t)d * 2048 + c) = y;
  }
}

// C[m,n] = sum_k A[m,k]*B[n,k] + bias[n];  A:[M,K] bf16, B:[N,K] bf16, row-major.
// EPI==1: scatter bf16 into q/k/v [B*NH][S][HD].  EPI==2: f32 into dout[M][N].
template<int EPI>
__global__ __launch_bounds__(256)
void gemm_bt(const ushort* __restrict__ A, const ushort* __restrict__ B,
             const float* __restrict__ bias,
             ushort* __restrict__ dq, ushort* __restrict__ dk, ushort* __restrict__ dv,
             float* __restrict__ dout,
             int M, int N, int K)
{
  __shared__ ushort Alds[2][128*32];
  __shared__ ushort Blds[2][128*32];
  const int t = threadIdx.x;
  const int w = t >> 6, l = t & 63;
  const int lr = l & 15, lg = l >> 4;
  const int m0 = blockIdx.x * 128, n0 = blockIdx.y * 128;
  const int wm = (w >> 1) * 64, wn = (w & 1) * 64;

  f32x4 acc[4][4] = {};

  auto stage = [&](int buf, int kt){
#pragma unroll
    for (int i = 0; i < 2; i++){
      const int row = i*64 + w*16 + (l >> 2);
      const int ce  = (l & 3) * 8;
      load_lds16(A + (size_t)(m0 + row) * K + kt*32 + ce, &Alds[buf][(i*64 + w*16) * 32]);
      load_lds16(B + (size_t)(n0 + row) * K + kt*32 + ce, &Blds[buf][(i*64 + w*16) * 32]);
    }
  };

  const int nk = K >> 5;
  int cur = 0;
  stage(0, 0);
  __syncthreads();
  for (int kt = 0; kt < nk; kt++){
    if (kt + 1 < nk) stage(cur ^ 1, kt + 1);
    bfrag af[4], bfv[4];
#pragma unroll
    for (int f = 0; f < 4; f++){
      af[f]  = *(const bfrag*)&Alds[cur][(wm + f*16 + lr) * 32 + lg * 8];
      bfv[f] = *(const bfrag*)&Blds[cur][(wn + f*16 + lr) * 32 + lg * 8];
    }
#pragma unroll
    for (int mf = 0; mf < 4; mf++)
#pragma unroll
      for (int nf = 0; nf < 4; nf++)
        acc[mf][nf] = __builtin_amdgcn_mfma_f32_16x16x32_bf16(af[mf], bfv[nf], acc[mf][nf], 0, 0, 0);
    __syncthreads();
    cur ^= 1;
  }

#pragma unroll
  for (int mf = 0; mf < 4; mf++){
#pragma unroll
    for (int nf = 0; nf < 4; nf++){
      const int col = n0 + wn + nf*16 + lr;
      const float bs = bias[col];
#pragma unroll
      for (int r = 0; r < 4; r++){
        const int row = m0 + wm + mf*16 + lg*4 + r;
        const float vv = acc[mf][nf][r] + bs;
        if (EPI == 1){
          const int which = col >> 10;
          const int hd = col & 1023;
          const int bb = row >> 11, s = row & 2047;
          const int bh = (bb << 4) + (hd >> 6);
          ushort* dst = (which == 0) ? dq : (which == 1) ? dk : dv;
          dst[((size_t)bh * 2048 + s) * 64 + (hd & 63)] = f2bf(vv);
        } else {
          dout[(size_t)row * N + col] = vv;
        }
      }
    }
  }
}

// Flash attention v9: swapped orientation (sa = mfma(K,Q): col=lr=q), with
// K-row PERMUTATION rho(nf,m) = (nf&1)*32 + (m>>2)*8 + (nf>>1)*4 + (m&3) in
// the A-operand reads. Softmax is permutation-invariant over k, and the
// resulting per-lane k-coverage {lg*8+0..7} u {32+lg*8+0..7} IS the PV
// B-fragment layout -> P fragment built from the lane's OWN registers.
// NO cross-lane exchange at all (the v8 permlane-direction risk is gone).
__global__ __launch_bounds__(512, 4)
void flash_attn(const ushort* __restrict__ q, const ushort* __restrict__ k,
                const ushort* __restrict__ vt, const float* __restrict__ mask2,
                ushort* __restrict__ ao)
{
  __shared__ ushort Klds[2][64*64];
  __shared__ ushort Vlds[2][64*64];
  const int t = threadIdx.x;
  const int w = t >> 6, l = t & 63;
  const int lr = l & 15, lg = l >> 4;
  const int bh = blockIdx.y;
  const int b = bh >> 4, h = bh & 15;
  const int q0 = blockIdx.x * 128;
  const ushort* qb  = q  + (size_t)bh * 2048 * 64;
  const ushort* kb  = k  + (size_t)bh * 2048 * 64;
  const ushort* vtb = vt + (size_t)bh * 64 * 2048;
  const float* mb = mask2 + b * 2048;            // premultiplied by LOG2E

  // 512 threads stage one 64x64 K tile + one 64x64 Vt tile (1 load each).
  // Linear LDS dest (t*16); source column pre-permuted with SWZ(row).
  const int srow = t >> 3;           // 0..63
  const int soff = ((t & 7) * 16) ^ SWZ(srow);

  auto stageKV = [&](int buf, int kv0){
    load_lds16((const char*)(kb + (size_t)kv0 * 64) + srow*128 + soff,
               (char*)&Klds[buf][0] + w*1024);
    load_lds16((const char*)vtb + (size_t)srow * 4096 + kv0*2 + soff,
               (char*)&Vlds[buf][0] + w*1024);
  };

  bfrag qf[2];
#pragma unroll
  for (int kf = 0; kf < 2; kf++){
    const int row = q0 + w*16 + lr;
    qf[kf] = *(const bfrag*)(qb + (size_t)row * 64 + kf*32 + lg*8);
  }

  float mrun = -1e30f, lsum = 0.f;
  f32x4 oacc[4] = {};

  const float SC2 = 0.125f * LOG2E;
  const int rbase = (lr >> 2) * 8 + (lr & 3);    // rho minus nf terms

  stageKV(0, 0);

  int cur = 0;
  for (int kv0 = 0; kv0 < 2048; kv0 += 64){
    __syncthreads();               // drains prev prefetch + protects buffers
    if (kv0 + 64 < 2048) stageKV(cur ^ 1, kv0 + 64);

    // mask for this lane's kv set: kv = (nf&1)*32 + lg*8 + (nf>>1)*4 + r
    float4 mk[4];
#pragma unroll
    for (int nf = 0; nf < 4; nf++)
      mk[nf] = *(const float4*)(mb + kv0 + ((nf & 1) << 5) + (lg << 3) + ((nf >> 1) << 2));

    // S^T = K Q^T with permuted K-row reads: reg r of sa[nf] holds
    // S[kv = (nf&1)*32 + lg*8 + (nf>>1)*4 + r][q = lr]
    bfrag bk[4][2];
#pragma unroll
    for (int nf = 0; nf < 4; nf++){
      const int rho = ((nf & 1) << 5) + ((nf >> 1) << 2) + rbase;
      const int rsw = SWZ(rho);
#pragma unroll
      for (int kf = 0; kf < 2; kf++){
        const int kbyte = kf*64 + lg*16;
        bk[nf][kf] = *(const bfrag*)((const char*)&Klds[cur][0] + rho*128 + (kbyte ^ rsw));
      }
    }
    f32x4 sa[4] = {};
#pragma unroll
    for (int nf = 0; nf < 4; nf++)
#pragma unroll
      for (int kf = 0; kf < 2; kf++)
        sa[nf] = __builtin_amdgcn_mfma_f32_16x16x32_bf16(bk[nf][kf], qf[kf], sa[nf], 0, 0, 0);

    // scaled scores (exp2 domain); per-lane max over own 16 k's
    float sc[4][4];
#pragma unroll
    for (int nf = 0; nf < 4; nf++){
      sc[nf][0] = fmaf(sa[nf][0], SC2, mk[nf].x);
      sc[nf][1] = fmaf(sa[nf][1], SC2, mk[nf].y);
      sc[nf][2] = fmaf(sa[nf][2], SC2, mk[nf].z);
      sc[nf][3] = fmaf(sa[nf][3], SC2, mk[nf].w);
    }
    float mx = sc[0][0];
#pragma unroll
    for (int nf = 0; nf < 4; nf++)
#pragma unroll
      for (int r = 0; r < 4; r++) mx = fmaxf(mx, sc[nf][r]);

    // defer-max (THR=8): row true max = max over the 4 lanes sharing lr
    if (__any(mx > mrun + 8.f)){
      const float mnew = fmaxf(mrun, redq_max(mx));
      const float c = __builtin_amdgcn_exp2f(mrun - mnew);
      mrun = mnew;
      lsum *= c;
#pragma unroll
      for (int nf = 0; nf < 4; nf++) oacc[nf] *= c;
    }

    // P = exp2(sc - mrun); per-lane partial sum; pack DIRECTLY into the PV
    // B-fragment: ap[kf] = [p[kf][0..3] | p[kf+2][0..3]] as 4 u32 bf16-pairs.
    float p[4][4];
    float ps = 0.f;
#pragma unroll
    for (int nf = 0; nf < 4; nf++)
#pragma unroll
      for (int r = 0; r < 4; r++){
        p[nf][r] = __builtin_amdgcn_exp2f(sc[nf][r] - mrun);
        ps += p[nf][r];
      }
    lsum += ps;

    bfrag ap[2];
#pragma unroll
    for (int kf = 0; kf < 2; kf++){
      uint4v tv = { cvt_pk_bf16(p[kf][0],   p[kf][1]),
                    cvt_pk_bf16(p[kf][2],   p[kf][3]),
                    cvt_pk_bf16(p[kf+2][0], p[kf+2][1]),
                    cvt_pk_bf16(p[kf+2][2], p[kf+2][3]) };
      ap[kf] = __builtin_bit_cast(bfrag, tv);
    }

    // O^T += Vt P : A = Vt frag (m=d), B = P (n=q) -> lane holds O[q=lr][d]
    bfrag bv[4][2];
#pragma unroll
    for (int nf = 0; nf < 4; nf++)
#pragma unroll
      for (int kf = 0; kf < 2; kf++){
        const int d = nf*16 + lr;
        const int kbyte = kf*64 + lg*16;
        bv[nf][kf] = *(const bfrag*)((const char*)&Vlds[cur][0] + d*128 + (kbyte ^ SWZ(d)));
      }
#pragma unroll
    for (int nf = 0; nf < 4; nf++)
#pragma unroll
      for (int kf = 0; kf < 2; kf++)
        oacc[nf] = __builtin_amdgcn_mfma_f32_16x16x32_bf16(bv[nf][kf], ap[kf], oacc[nf], 0, 0, 0);

    cur ^= 1;
  }

  // epilogue: finish row-sum across the 4 lanes sharing lr, divide, store 8B
  const float inv = 1.f / redq_sum(lsum);
  ushort* orow = ao + (size_t)(b*2048 + q0 + w*16 + lr) * 1024 + h*64 + lg*4;
#pragma unroll
  for (int nf = 0; nf < 4; nf++){
    const uint32_t w01 = cvt_pk_bf16(oacc[nf][0] * inv, oacc[nf][1] * inv);
    const uint32_t w23 = cvt_pk_bf16(oacc[nf][2] * inv, oacc[nf][3] * inv);
    uint2v vv = {w01, w23};
    *(uint2v*)(orow + nf*16) = vv;
  }
}

extern "C" void kernel_launch(void* const* d_in, const int* in_sizes, int n_in,
                              void* d_out, int out_size, void* d_ws, size_t ws_size,
                              hipStream_t stream)
{
  (void)in_sizes; (void)n_in; (void)out_size; (void)ws_size;
  const float* hs   = (const float*)d_in[0];
  const float* mask = (const float*)d_in[1];
  const float* wqkv = (const float*)d_in[2];
  const float* bqkv = (const float*)d_in[3];
  const float* wout = (const float*)d_in[4];
  const float* bout = (const float*)d_in[5];
  float* out = (float*)d_out;

  char* ws = (char*)d_ws;
  ushort* hs_bf = (ushort*)(ws);                 // 4096*1024   bf16 (8 MB)
  ushort* w1_bf = (ushort*)(ws + 8388608);       // 3072*1024   bf16 (6 MB)
  ushort* w2_bf = (ushort*)(ws + 14680064);      // 1024*1024   bf16 (2 MB)
  ushort* q_bf  = (ushort*)(ws + 16777216);      // [32][2048][64] bf16 (8 MB)
  ushort* k_bf  = (ushort*)(ws + 25165824);      // [32][2048][64] bf16 (8 MB)
  ushort* v_bf  = (ushort*)(ws + 33554432);      // [32][2048][64] bf16 (8 MB)
  ushort* vt_bf = (ushort*)(ws + 41943040);      // [32][64][2048] bf16 (8 MB)
  ushort* ao_bf = (ushort*)(ws + 50331648);      // [4096][1024] bf16 (8 MB)
  float*  mask2 = (float*)(ws + 58720256);       // [2][2048] f32 * LOG2E (16 KB)

  cast_all<<<8196, 256, 0, stream>>>(hs, wqkv, wout, mask, (ushort*)ws, mask2);

  gemm_bt<1><<<dim3(32, 24), 256, 0, stream>>>(hs_bf, w1_bf, bqkv,
                                               q_bf, k_bf, v_bf, nullptr,
                                               4096, 3072, 1024);
  transpose_v<<<dim3(32, 32), 256, 0, stream>>>(v_bf, vt_bf);
  flash_attn<<<dim3(16, 32), 512, 0, stream>>>(q_bf, k_bf, vt_bf, mask2, ao_bf);
  gemm_bt<2><<<dim3(32, 8), 256, 0, stream>>>(ao_bf, w2_bf, bout,
                                              nullptr, nullptr, nullptr, out,
                                              4096, 1024, 1024);
}

// Round 10
// 127.783 us; speedup vs baseline: 1.6925x; 1.0060x over previous
//
#include <hip/hip_runtime.h>
#include <stdint.h>

typedef short bfrag __attribute__((ext_vector_type(8)));   // 8 bf16 = 4 VGPRs
typedef float f32x4 __attribute__((ext_vector_type(4)));
typedef uint  uint4v __attribute__((ext_vector_type(4)));
typedef uint  uint2v __attribute__((ext_vector_type(2)));

#define LOG2E 1.4426950408889634f
// LDS row swizzle: spreads rows {0-3 mod 8} AND consecutive rows across slots.
#define SWZ(row) ((((row) & 3) | (((row) >> 1) & 4)) << 4)

__device__ __forceinline__ ushort f2bf(float x){
  union { float f; uint32_t u; } c; c.f = x;
  uint32_t r = (c.u + 0x7fffu + ((c.u >> 16) & 1u)) >> 16;
  return (ushort)r;
}

__device__ __forceinline__ uint32_t cvt_pk_bf16(float lo, float hi){
  uint32_t r;
  asm("v_cvt_pk_bf16_f32 %0, %1, %2" : "=v"(r) : "v"(lo), "v"(hi));
  return r;
}

// cross-lane reduce over lanes {lr, lr+16, lr+32, lr+48} — off the hot path.
__device__ __forceinline__ float redq_max(float x){
  x = fmaxf(x, __shfl_xor(x, 16));
  x = fmaxf(x, __shfl_xor(x, 32));
  return x;
}
__device__ __forceinline__ float redq_sum(float x){
  x += __shfl_xor(x, 16);
  x += __shfl_xor(x, 32);
  return x;
}

__device__ __forceinline__ void load_lds16(const void* g, void* l){
  __builtin_amdgcn_global_load_lds((const __attribute__((address_space(1))) void*)g,
                                   (__attribute__((address_space(3))) void*)l,
                                   16, 0, 0);
}

// Merged cast: hs|wqkv|wout -> bf16 (contiguous in ws), plus mask*LOG2E -> f32.
__global__ void cast_all(const float* __restrict__ hs, const float* __restrict__ wqkv,
                         const float* __restrict__ wout, const float* __restrict__ mask,
                         ushort* __restrict__ out, float* __restrict__ mask2){
  const int i = blockIdx.x * blockDim.x + threadIdx.x;     // float4 index
  if (i < 2097152){
    float4 f;
    if (i < 1048576)       f = ((const float4*)hs)[i];
    else if (i < 1835008)  f = ((const float4*)wqkv)[i - 1048576];
    else                   f = ((const float4*)wout)[i - 1835008];
    ushort4 u;
    u.x = f2bf(f.x); u.y = f2bf(f.y); u.z = f2bf(f.z); u.w = f2bf(f.w);
    ((ushort4*)out)[i] = u;
  } else {
    const int j = i - 2097152;                             // 1024 float4s of mask
    float4 m = ((const float4*)mask)[j];
    m.x *= LOG2E; m.y *= LOG2E; m.z *= LOG2E; m.w *= LOG2E;
    ((float4*)mask2)[j] = m;
  }
}

// C[m,n] = sum_k A[m,k]*B[n,k] + bias[n];  A:[M,K] bf16, B:[N,K] bf16, row-major.
// EPI==1: scatter bf16 into q/k [B*NH][S][HD] and V TRANSPOSED [B*NH][HD][S]
//         (packed 8B stores: r=0..3 are consecutive s).  EPI==2: f32 dout[M][N].
template<int EPI>
__global__ __launch_bounds__(256)
void gemm_bt(const ushort* __restrict__ A, const ushort* __restrict__ B,
             const float* __restrict__ bias,
             ushort* __restrict__ dq, ushort* __restrict__ dk, ushort* __restrict__ dvt,
             float* __restrict__ dout,
             int M, int N, int K)
{
  __shared__ ushort Alds[2][128*32];
  __shared__ ushort Blds[2][128*32];
  const int t = threadIdx.x;
  const int w = t >> 6, l = t & 63;
  const int lr = l & 15, lg = l >> 4;
  const int m0 = blockIdx.x * 128, n0 = blockIdx.y * 128;
  const int wm = (w >> 1) * 64, wn = (w & 1) * 64;

  f32x4 acc[4][4] = {};

  auto stage = [&](int buf, int kt){
#pragma unroll
    for (int i = 0; i < 2; i++){
      const int row = i*64 + w*16 + (l >> 2);
      const int ce  = (l & 3) * 8;
      load_lds16(A + (size_t)(m0 + row) * K + kt*32 + ce, &Alds[buf][(i*64 + w*16) * 32]);
      load_lds16(B + (size_t)(n0 + row) * K + kt*32 + ce, &Blds[buf][(i*64 + w*16) * 32]);
    }
  };

  const int nk = K >> 5;
  int cur = 0;
  stage(0, 0);
  __syncthreads();
  for (int kt = 0; kt < nk; kt++){
    if (kt + 1 < nk) stage(cur ^ 1, kt + 1);
    bfrag af[4], bfv[4];
#pragma unroll
    for (int f = 0; f < 4; f++){
      af[f]  = *(const bfrag*)&Alds[cur][(wm + f*16 + lr) * 32 + lg * 8];
      bfv[f] = *(const bfrag*)&Blds[cur][(wn + f*16 + lr) * 32 + lg * 8];
    }
#pragma unroll
    for (int mf = 0; mf < 4; mf++)
#pragma unroll
      for (int nf = 0; nf < 4; nf++)
        acc[mf][nf] = __builtin_amdgcn_mfma_f32_16x16x32_bf16(af[mf], bfv[nf], acc[mf][nf], 0, 0, 0);
    __syncthreads();
    cur ^= 1;
  }

#pragma unroll
  for (int mf = 0; mf < 4; mf++){
#pragma unroll
    for (int nf = 0; nf < 4; nf++){
      const int col = n0 + wn + nf*16 + lr;
      const float bs = bias[col];
      if (EPI == 1){
        const int which = col >> 10;
        const int hd = col & 1023;
        const int bh = ((m0 >> 11) << 4) + (hd >> 6);   // m0 block is within one b
        const int s0 = (m0 + wm + mf*16 + lg*4) & 2047;
        if (which == 2){
          // V transposed: [bh][d][s], r=0..3 consecutive s -> one 8B store
          const float v0 = acc[mf][nf][0] + bs, v1 = acc[mf][nf][1] + bs;
          const float v2 = acc[mf][nf][2] + bs, v3 = acc[mf][nf][3] + bs;
          uint2v pv = { cvt_pk_bf16(v0, v1), cvt_pk_bf16(v2, v3) };
          *(uint2v*)(dvt + ((size_t)bh * 64 + (hd & 63)) * 2048 + s0) = pv;
        } else {
          ushort* dst = (which == 0) ? dq : dk;
#pragma unroll
          for (int r = 0; r < 4; r++)
            dst[((size_t)bh * 2048 + s0 + r) * 64 + (hd & 63)] = f2bf(acc[mf][nf][r] + bs);
        }
      } else {
#pragma unroll
        for (int r = 0; r < 4; r++){
          const int row = m0 + wm + mf*16 + lg*4 + r;
          dout[(size_t)row * N + col] = acc[mf][nf][r] + bs;
        }
      }
    }
  }
}

// Flash attention v10: 4 waves x 32 q-rows each (2 q-fragments per wave) —
// every bk/bv LDS read now feeds TWO MFMAs (register blocking), halving the
// DS-pipe load per unit work. QBLK=128, 256 threads, grid (16,32).
// Swapped orientation + K-row permutation + in-register P (from v9).
__global__ __launch_bounds__(256, 2)
void flash_attn(const ushort* __restrict__ q, const ushort* __restrict__ k,
                const ushort* __restrict__ vt, const float* __restrict__ mask2,
                ushort* __restrict__ ao)
{
  __shared__ ushort Klds[2][64*64];
  __shared__ ushort Vlds[2][64*64];
  const int t = threadIdx.x;
  const int w = t >> 6, l = t & 63;
  const int lr = l & 15, lg = l >> 4;
  const int bh = blockIdx.y;
  const int b = bh >> 4, h = bh & 15;
  const int q0 = blockIdx.x * 128;
  const ushort* qb  = q  + (size_t)bh * 2048 * 64;
  const ushort* kb  = k  + (size_t)bh * 2048 * 64;
  const ushort* vtb = vt + (size_t)bh * 64 * 2048;
  const float* mb = mask2 + b * 2048;            // premultiplied by LOG2E

  // 256 threads stage 8KB K + 8KB Vt per tile: 2 gload_lds each per buffer.
  const int srow0 = t >> 3;          // 0..31
  const int scol  = (t & 7) * 16;

  auto stageKV = [&](int buf, int kv0){
#pragma unroll
    for (int i = 0; i < 2; i++){
      const int row = srow0 + i*32;
      const int off = scol ^ SWZ(row);
      load_lds16((const char*)(kb + (size_t)kv0 * 64) + row*128 + off,
                 (char*)&Klds[buf][0] + i*4096 + w*1024);
      load_lds16((const char*)vtb + (size_t)row * 4096 + kv0*2 + off,
                 (char*)&Vlds[buf][0] + i*4096 + w*1024);
    }
  };

  bfrag qf[2][2];
#pragma unroll
  for (int qg = 0; qg < 2; qg++)
#pragma unroll
    for (int kf = 0; kf < 2; kf++){
      const int row = q0 + w*32 + qg*16 + lr;
      qf[qg][kf] = *(const bfrag*)(qb + (size_t)row * 64 + kf*32 + lg*8);
    }

  float mrun[2] = {-1e30f, -1e30f}, lsum[2] = {0.f, 0.f};
  f32x4 oacc[2][4] = {};

  const float SC2 = 0.125f * LOG2E;
  const int rbase = (lr >> 2) * 8 + (lr & 3);    // rho minus nf terms

  stageKV(0, 0);

  int cur = 0;
  for (int kv0 = 0; kv0 < 2048; kv0 += 64){
    __syncthreads();               // drains prev prefetch + protects buffers
    if (kv0 + 64 < 2048) stageKV(cur ^ 1, kv0 + 64);

    // mask for this lane's kv set: kv = (nf&1)*32 + lg*8 + (nf>>1)*4 + r
    float4 mk[4];
#pragma unroll
    for (int nf = 0; nf < 4; nf++)
      mk[nf] = *(const float4*)(mb + kv0 + ((nf & 1) << 5) + (lg << 3) + ((nf >> 1) << 2));

    // S^T = K Q^T with permuted K-row reads (shared across both q-groups)
    bfrag bk[4][2];
#pragma unroll
    for (int nf = 0; nf < 4; nf++){
      const int rho = ((nf & 1) << 5) + ((nf >> 1) << 2) + rbase;
      const int rsw = SWZ(rho);
#pragma unroll
      for (int kf = 0; kf < 2; kf++){
        const int kbyte = kf*64 + lg*16;
        bk[nf][kf] = *(const bfrag*)((const char*)&Klds[cur][0] + rho*128 + (kbyte ^ rsw));
      }
    }
    f32x4 sa[2][4] = {};
#pragma unroll
    for (int qg = 0; qg < 2; qg++)
#pragma unroll
      for (int nf = 0; nf < 4; nf++)
#pragma unroll
        for (int kf = 0; kf < 2; kf++)
          sa[qg][nf] = __builtin_amdgcn_mfma_f32_16x16x32_bf16(bk[nf][kf], qf[qg][kf], sa[qg][nf], 0, 0, 0);

    // scaled scores (exp2 domain); per-lane max over own 16 k's per q-group
    float sc[2][4][4], mx[2];
#pragma unroll
    for (int qg = 0; qg < 2; qg++){
#pragma unroll
      for (int nf = 0; nf < 4; nf++){
        sc[qg][nf][0] = fmaf(sa[qg][nf][0], SC2, mk[nf].x);
        sc[qg][nf][1] = fmaf(sa[qg][nf][1], SC2, mk[nf].y);
        sc[qg][nf][2] = fmaf(sa[qg][nf][2], SC2, mk[nf].z);
        sc[qg][nf][3] = fmaf(sa[qg][nf][3], SC2, mk[nf].w);
      }
      float m01 = fmaxf(fmaxf(sc[qg][0][0], sc[qg][0][1]), fmaxf(sc[qg][0][2], sc[qg][0][3]));
#pragma unroll
      for (int nf = 1; nf < 4; nf++)
#pragma unroll
        for (int r = 0; r < 4; r++) m01 = fmaxf(m01, sc[qg][nf][r]);
      mx[qg] = m01;
    }

    // defer-max (THR=8)
    const bool grew = (mx[0] > mrun[0] + 8.f) | (mx[1] > mrun[1] + 8.f);
    if (__any(grew)){
#pragma unroll
      for (int qg = 0; qg < 2; qg++){
        const float mnew = fmaxf(mrun[qg], redq_max(mx[qg]));
        const float c = __builtin_amdgcn_exp2f(mrun[qg] - mnew);
        mrun[qg] = mnew;
        lsum[qg] *= c;
#pragma unroll
        for (int nf = 0; nf < 4; nf++) oacc[qg][nf] *= c;
      }
    }

    // P = exp2(sc - mrun) in place; partial sums; pack into PV B-fragments
    bfrag ap[2][2];
#pragma unroll
    for (int qg = 0; qg < 2; qg++){
      float ps = 0.f;
#pragma unroll
      for (int nf = 0; nf < 4; nf++)
#pragma unroll
        for (int r = 0; r < 4; r++){
          sc[qg][nf][r] = __builtin_amdgcn_exp2f(sc[qg][nf][r] - mrun[qg]);
          ps += sc[qg][nf][r];
        }
      lsum[qg] += ps;
#pragma unroll
      for (int kf = 0; kf < 2; kf++){
        uint4v tv = { cvt_pk_bf16(sc[qg][kf][0],   sc[qg][kf][1]),
                      cvt_pk_bf16(sc[qg][kf][2],   sc[qg][kf][3]),
                      cvt_pk_bf16(sc[qg][kf+2][0], sc[qg][kf+2][1]),
                      cvt_pk_bf16(sc[qg][kf+2][2], sc[qg][kf+2][3]) };
        ap[qg][kf] = __builtin_bit_cast(bfrag, tv);
      }
    }

    // O^T += Vt P (bv shared across q-groups)
    bfrag bv[4][2];
#pragma unroll
    for (int nf = 0; nf < 4; nf++)
#pragma unroll
      for (int kf = 0; kf < 2; kf++){
        const int d = nf*16 + lr;
        const int kbyte = kf*64 + lg*16;
        bv[nf][kf] = *(const bfrag*)((const char*)&Vlds[cur][0] + d*128 + (kbyte ^ SWZ(d)));
      }
#pragma unroll
    for (int qg = 0; qg < 2; qg++)
#pragma unroll
      for (int nf = 0; nf < 4; nf++)
#pragma unroll
        for (int kf = 0; kf < 2; kf++)
          oacc[qg][nf] = __builtin_amdgcn_mfma_f32_16x16x32_bf16(bv[nf][kf], ap[qg][kf], oacc[qg][nf], 0, 0, 0);

    cur ^= 1;
  }

  // epilogue per q-group: finish row-sum, divide, store 8B
#pragma unroll
  for (int qg = 0; qg < 2; qg++){
    const float inv = 1.f / redq_sum(lsum[qg]);
    ushort* orow = ao + (size_t)(b*2048 + q0 + w*32 + qg*16 + lr) * 1024 + h*64 + lg*4;
#pragma unroll
    for (int nf = 0; nf < 4; nf++){
      const uint32_t w01 = cvt_pk_bf16(oacc[qg][nf][0] * inv, oacc[qg][nf][1] * inv);
      const uint32_t w23 = cvt_pk_bf16(oacc[qg][nf][2] * inv, oacc[qg][nf][3] * inv);
      uint2v vv = {w01, w23};
      *(uint2v*)(orow + nf*16) = vv;
    }
  }
}

extern "C" void kernel_launch(void* const* d_in, const int* in_sizes, int n_in,
                              void* d_out, int out_size, void* d_ws, size_t ws_size,
                              hipStream_t stream)
{
  (void)in_sizes; (void)n_in; (void)out_size; (void)ws_size;
  const float* hs   = (const float*)d_in[0];
  const float* mask = (const float*)d_in[1];
  const float* wqkv = (const float*)d_in[2];
  const float* bqkv = (const float*)d_in[3];
  const float* wout = (const float*)d_in[4];
  const float* bout = (const float*)d_in[5];
  float* out = (float*)d_out;

  char* ws = (char*)d_ws;
  ushort* hs_bf = (ushort*)(ws);                 // 4096*1024   bf16 (8 MB)
  ushort* w1_bf = (ushort*)(ws + 8388608);       // 3072*1024   bf16 (6 MB)
  ushort* w2_bf = (ushort*)(ws + 14680064);      // 1024*1024   bf16 (2 MB)
  ushort* q_bf  = (ushort*)(ws + 16777216);      // [32][2048][64] bf16 (8 MB)
  ushort* k_bf  = (ushort*)(ws + 25165824);      // [32][2048][64] bf16 (8 MB)
  ushort* vt_bf = (ushort*)(ws + 33554432);      // [32][64][2048] bf16 (8 MB)
  ushort* ao_bf = (ushort*)(ws + 41943040);      // [4096][1024] bf16 (8 MB)
  float*  mask2 = (float*)(ws + 50331648);       // [2][2048] f32 * LOG2E (16 KB)

  cast_all<<<8196, 256, 0, stream>>>(hs, wqkv, wout, mask, (ushort*)ws, mask2);

  gemm_bt<1><<<dim3(32, 24), 256, 0, stream>>>(hs_bf, w1_bf, bqkv,
                                               q_bf, k_bf, vt_bf, nullptr,
                                               4096, 3072, 1024);
  flash_attn<<<dim3(16, 32), 256, 0, stream>>>(q_bf, k_bf, vt_bf, mask2, ao_bf);
  gemm_bt<2><<<dim3(32, 8), 256, 0, stream>>>(ao_bf, w2_bf, bout,
                                              nullptr, nullptr, nullptr, out,
                                              4096, 1024, 1024);
}